// Round 16
// baseline (39493.073 us; speedup 1.0000x reference)
//
#include <hip/hip_runtime.h>
#include <hip/hip_bf16.h>
#include <math.h>

#define B    32
#define EMBD 1024
#define HID  1024
#define G    4096
#define V    32000
#define TS   128
#define XROW (TS + 1)
#define KSL  8
#define NFCB 250
#define NFM  500
#define GAPT 2e-3f
#define GWM  (4096 * 1024)

typedef short bf16x8 __attribute__((ext_vector_type(8)));
typedef float f32x4  __attribute__((ext_vector_type(4)));

#define FMA4(acc, W_, V_) \
  acc = fmaf((W_).x,(V_).x, fmaf((W_).y,(V_).y, fmaf((W_).z,(V_).z, fmaf((W_).w,(V_).w,(acc)))))

__device__ __forceinline__ unsigned short f2bu(float x) {
    __hip_bfloat16 b = __float2bfloat16(x);
    return *reinterpret_cast<unsigned short*>(&b);
}
__device__ __forceinline__ float b2f(unsigned short u) {
    union { unsigned int v; float f; } c; c.v = ((unsigned int)u) << 16; return c.f;
}
__device__ __forceinline__ void ins2(float m, int i, float& m1, int& i1,
                                     float& m2, int& i2) {
    if (m > m1 || (m == m1 && i < i1)) { m2 = m1; i2 = i1; m1 = m; i1 = i; }
    else if (m > m2 || (m == m2 && i < i2)) { m2 = m; i2 = i; }
}
__device__ __forceinline__ size_t pidx_act(int b, int jh) {
    const int kb = jh >> 5, kslot = (jh >> 3) & 3, e = jh & 7;
    const int lane = kslot * 16 + (b & 15);
    return ((((size_t)(b >> 4)) * 32 + kb) * 64 + lane) * 8 + e;
}

// ---------------- FC weight bf16 fragment-major reorder (R14-verified) -----
__global__ __launch_bounds__(256) void k_conv(
    const float* __restrict__ W, unsigned short* __restrict__ out)
{
    const int ngrp = V * HID / 8;
    for (int o = blockIdx.x * 256 + threadIdx.x; o < ngrp; o += gridDim.x * 256) {
        const int lane = o & 63, kb = (o >> 6) & 31, tile = o >> 11;
        const int row = tile * 16 + (lane & 15);
        const int k0  = kb * 32 + (lane >> 4) * 8;
        const float4 v0 = *(const float4*)(W + (size_t)row * 1024 + k0);
        const float4 v1 = *(const float4*)(W + (size_t)row * 1024 + k0 + 4);
        ushort4 a, b;
        a.x = f2bu(v0.x); a.y = f2bu(v0.y); a.z = f2bu(v0.z); a.w = f2bu(v0.w);
        b.x = f2bu(v1.x); b.y = f2bu(v1.y); b.z = f2bu(v1.z); b.w = f2bu(v1.w);
        ((ushort4*)out)[o * 2]     = a;
        ((ushort4*)out)[o * 2 + 1] = b;
    }
}

// ---------------- gate weight bf16x2 reorder WITH gate-interleaved rows ----
// permuted row j': group g=j'>>7 holds jh in [g*32,g*32+32) for all 4 gates.
// actual W row = gate*1024 + jh, gate=(j'>>5)&3, jh=(j'>>7)*32+(j'&31).
__global__ __launch_bounds__(256) void k_conv_g(
    const float* __restrict__ W, unsigned short* __restrict__ hi,
    unsigned short* __restrict__ mid)
{
    const int ngrp = GWM / 8;
    for (int o = blockIdx.x * 256 + threadIdx.x; o < ngrp; o += gridDim.x * 256) {
        const int lane = o & 63, kb = (o >> 6) & 31, tile = o >> 11;
        const int jp = tile * 16 + (lane & 15);      // permuted row
        const int gate = (jp >> 5) & 3;
        const int jh   = (jp >> 7) * 32 + (jp & 31);
        const int row  = gate * 1024 + jh;
        const int k0  = kb * 32 + (lane >> 4) * 8;
#pragma unroll
        for (int q = 0; q < 2; q++) {
            const float4 v = *(const float4*)(W + (size_t)row * 1024 + k0 + q * 4);
            ushort4 h, m;
            h.x = f2bu(v.x); m.x = f2bu(v.x - b2f(h.x));
            h.y = f2bu(v.y); m.y = f2bu(v.y - b2f(h.y));
            h.z = f2bu(v.z); m.z = f2bu(v.z - b2f(h.z));
            h.w = f2bu(v.w); m.w = f2bu(v.w - b2f(h.w));
            ((ushort4*)hi)[o * 2 + q]  = h;
            ((ushort4*)mid)[o * 2 + q] = m;
        }
    }
}

// ---------------- init (mfma tier): states=0, planes, counters ----------------
__global__ __launch_bounds__(256) void k_init_m(
    const int* __restrict__ x, const float* __restrict__ emb,
    float* __restrict__ xcur, float* __restrict__ st,
    unsigned short* __restrict__ xHi, unsigned short* __restrict__ xMid,
    unsigned short* __restrict__ h0Hi, unsigned short* __restrict__ h0Mid,
    unsigned short* __restrict__ h1Hi, unsigned short* __restrict__ h1Mid,
    int* __restrict__ cnt)
{
    const int b = blockIdx.x, tid = threadIdx.x;
    float4 z = {0.f, 0.f, 0.f, 0.f};
#pragma unroll
    for (int q = 0; q < 4; q++)
        ((float4*)(st + (size_t)q * B * HID + (size_t)b * HID))[tid] = z;
    const int tok = x[b * XROW];
    const float4 ev = ((const float4*)(emb + (size_t)tok * EMBD))[tid];
    ((float4*)(xcur + (size_t)b * EMBD))[tid] = ev;
    const int jh0 = tid * 4;
    const size_t p0 = pidx_act(b, jh0);
    const float e4[4] = {ev.x, ev.y, ev.z, ev.w};
#pragma unroll
    for (int q = 0; q < 4; q++) {
        const unsigned short h = f2bu(e4[q]);
        xHi[p0 + q]  = h;
        xMid[p0 + q] = f2bu(e4[q] - b2f(h));
        h0Hi[p0 + q] = 0; h0Mid[p0 + q] = 0;
        h1Hi[p0 + q] = 0; h1Mid[p0 + q] = 0;
    }
    if (b == 0 && tid < 96) cnt[tid] = 0;
}

// ---------------- fused MFMA LSTM layer: gates GEMM + per-jb act tail -------
// grid (32 jb, 8 ksb), block 512. Tail (last ksb per jb) does act for its
// 32 jh x 32 b slice, updating c and writing h planes (+ optional f32 h).
__global__ __launch_bounds__(512) void k_layer_mf(
    const unsigned short* __restrict__ WihHi, const unsigned short* __restrict__ WihMid,
    const unsigned short* __restrict__ WhhHi, const unsigned short* __restrict__ WhhMid,
    const unsigned short* __restrict__ xHi, const unsigned short* __restrict__ xMid,
    const unsigned short* __restrict__ hHi, const unsigned short* __restrict__ hMid,
    float* __restrict__ gpart2,
    const float* __restrict__ bih, const float* __restrict__ bhh,
    float* __restrict__ c2,
    unsigned short* __restrict__ oHi, unsigned short* __restrict__ oMid,
    float* __restrict__ h_f32,
    int* __restrict__ cnt)
{
    __shared__ int sLast;
    const int tid = threadIdx.x;
    const int wv  = tid >> 6;
    const int lane = tid & 63;
    const int jb  = blockIdx.x;
    const int ksb = blockIdx.y;
    const bool xp = (ksb < 4);
    const unsigned short* Ah = xp ? WihHi : WhhHi;
    const unsigned short* Am = xp ? WihMid : WhhMid;
    const unsigned short* Bh = xp ? xHi : hHi;
    const unsigned short* Bm = xp ? xMid : hMid;
    const int kb0 = (ksb & 3) * 8;
    const int tile = jb * 8 + wv;

    f32x4 acc0 = {0.f, 0.f, 0.f, 0.f};
    f32x4 acc1 = {0.f, 0.f, 0.f, 0.f};

#pragma unroll 4
    for (int i = 0; i < 8; i++) {
        const int kb = kb0 + i;
        const size_t aoff = (((size_t)tile * 32 + kb) * 64 + lane) * 8;
        const bf16x8 Avh = *(const bf16x8*)(Ah + aoff);
        const bf16x8 Avm = *(const bf16x8*)(Am + aoff);
        const size_t b0off = (((size_t)kb) * 64 + lane) * 8;
        const size_t b1off = (((size_t)(32 + kb)) * 64 + lane) * 8;
        const bf16x8 B0h = *(const bf16x8*)(Bh + b0off);
        const bf16x8 B0m = *(const bf16x8*)(Bm + b0off);
        const bf16x8 B1h = *(const bf16x8*)(Bh + b1off);
        const bf16x8 B1m = *(const bf16x8*)(Bm + b1off);
        acc0 = __builtin_amdgcn_mfma_f32_16x16x32_bf16(Avh, B0h, acc0, 0, 0, 0);
        acc1 = __builtin_amdgcn_mfma_f32_16x16x32_bf16(Avh, B1h, acc1, 0, 0, 0);
        acc0 = __builtin_amdgcn_mfma_f32_16x16x32_bf16(Avh, B0m, acc0, 0, 0, 0);
        acc1 = __builtin_amdgcn_mfma_f32_16x16x32_bf16(Avh, B1m, acc1, 0, 0, 0);
        acc0 = __builtin_amdgcn_mfma_f32_16x16x32_bf16(Avm, B0h, acc0, 0, 0, 0);
        acc1 = __builtin_amdgcn_mfma_f32_16x16x32_bf16(Avm, B1h, acc1, 0, 0, 0);
    }

    const int bcol = lane & 15;
#pragma unroll
    for (int r = 0; r < 4; r++) {
        const int jp = jb * 128 + wv * 16 + (lane >> 4) * 4 + r;
        gpart2[((size_t)ksb * G + jp) * B + bcol]      = acc0[r];
        gpart2[((size_t)ksb * G + jp) * B + 16 + bcol] = acc1[r];
    }

    // ---- tail: last ksb block of this jb does act for jh in [jb*32, +32) ----
    __threadfence();
    __syncthreads();
    if (tid == 0) {
        const int old = atomicAdd(&cnt[jb], 1);
        sLast = (old == 7) ? 1 : 0;
    }
    __syncthreads();
    if (!sLast) return;
    __threadfence();

    for (int u = tid; u < 1024; u += 512) {
        const int jl = u >> 5, b = u & 31;
        const int jh = jb * 32 + jl;
        float gs[4];
#pragma unroll
        for (int gate = 0; gate < 4; gate++) {
            const int jp = jb * 128 + gate * 32 + jl;
            float v = 0.f;
#pragma unroll
            for (int ks = 0; ks < KSL; ks++)
                v += gpart2[((size_t)ks * G + jp) * B + b];
            gs[gate] = v + bih[gate * 1024 + jh] + bhh[gate * 1024 + jh];
        }
        const float i = 1.f / (1.f + expf(-gs[0]));
        const float f = 1.f / (1.f + expf(-gs[1]));
        const float g = tanhf(gs[2]);
        const float o = 1.f / (1.f + expf(-gs[3]));
        const int ci = jh * 32 + b;
        const float cn = f * c2[ci] + i * g;
        c2[ci] = cn;
        const float hv = o * tanhf(cn);
        if (h_f32) h_f32[(size_t)b * HID + jh] = hv;
        const size_t p = pidx_act(b, jh);
        const unsigned short uh = f2bu(hv);
        oHi[p]  = uh;
        oMid[p] = f2bu(hv - b2f(uh));
    }
    if (tid == 0) { __threadfence(); cnt[jb] = 0; }
}

// ---------------- MFMA FC + fused fin tail ---------------------------------
// grid 500, block 512. cntF!=null => last block performs fin (reduce, guard,
// p-out, emb gather + x planes + xcur f32).
__global__ __launch_bounds__(512, 4) void k_fc_mfma(
    const unsigned short* __restrict__ Whr, const unsigned short* __restrict__ hbr,
    const float* __restrict__ bfc, const int* __restrict__ x, int t,
    float* __restrict__ psum, float* __restrict__ pm1, float* __restrict__ pm2,
    int* __restrict__ pi1, int* __restrict__ pi2, float* __restrict__ lt,
    const float* __restrict__ h1f, const float* __restrict__ Wfc,
    const float* __restrict__ emb, float* __restrict__ xcur,
    unsigned short* __restrict__ xHi, unsigned short* __restrict__ xMid,
    float* __restrict__ out, int* __restrict__ cntF)
{
    __shared__ float logits[64 * 33];
    __shared__ float pool[1632];
    __shared__ int   ipool[1088];
    __shared__ float fsum2[32], fm1a[32], fm2a[32];
    __shared__ int   fi1a[32], fi2a[32], fwn[32];
    __shared__ int   sLastF;

    const int tid = threadIdx.x;
    const int wv  = tid >> 6;
    const int kh  = wv >> 2;
    const int rg  = wv & 3;
    const int lane = tid & 63;
    const int jb  = blockIdx.x;
    const int j0  = jb * 64;

    const unsigned short* Ab = Whr + ((size_t)(jb * 4 + rg) * 32 * 64) * 8;

    f32x4 acc0 = {0.f, 0.f, 0.f, 0.f};
    f32x4 acc1 = {0.f, 0.f, 0.f, 0.f};

#pragma unroll 4
    for (int i = 0; i < 16; i++) {
        const int kb = kh * 16 + i;
        const bf16x8 Av = *(const bf16x8*)(Ab + ((size_t)kb * 64 + lane) * 8);
        const bf16x8 B0 = *(const bf16x8*)(hbr + (((size_t)kb) * 64 + lane) * 8);
        const bf16x8 B1 = *(const bf16x8*)(hbr + (((size_t)(32 + kb)) * 64 + lane) * 8);
        acc0 = __builtin_amdgcn_mfma_f32_16x16x32_bf16(Av, B0, acc0, 0, 0, 0);
        acc1 = __builtin_amdgcn_mfma_f32_16x16x32_bf16(Av, B1, acc1, 0, 0, 0);
    }

    const int rbase = rg * 16 + (lane >> 4) * 4;
    const int bcol  = lane & 15;
    if (kh == 0) {
#pragma unroll
        for (int r = 0; r < 4; r++) {
            const int rw = rbase + r;
            logits[rw * 33 + bcol]      = acc0[r] + bfc[j0 + rw];
            logits[rw * 33 + 16 + bcol] = acc1[r];
        }
    }
    __syncthreads();
    if (kh == 1) {
#pragma unroll
        for (int r = 0; r < 4; r++) {
            const int rw = rbase + r;
            logits[rw * 33 + bcol]      += acc0[r];
            logits[rw * 33 + 16 + bcol] += acc1[r] + bfc[j0 + rw];
        }
    }
    __syncthreads();

    {
        float* segS = pool; float* segM1 = pool + 512; float* segM2 = pool + 1024;
        int* segI1 = ipool; int* segI2 = ipool + 512;
        const int b = tid & 31, seg = tid >> 5;
        float ls = 0.f, m1 = -1e30f, m2 = -1e30f;
        int i1 = 0x7fffffff, i2 = 0x7fffffff;
#pragma unroll
        for (int i = 0; i < 4; i++) {
            const int rw = seg * 4 + i;
            const float l = logits[rw * 33 + b];
            ls += expf(l);
            ins2(l, j0 + rw, m1, i1, m2, i2);
        }
        segS[seg * 32 + b] = ls;
        segM1[seg * 32 + b] = m1; segI1[seg * 32 + b] = i1;
        segM2[seg * 32 + b] = m2; segI2[seg * 32 + b] = i2;
        __syncthreads();
        if (tid < 32) {
            float ts = 0.f, a1 = -1e30f, a2 = -1e30f;
            int x1 = 0x7fffffff, x2 = 0x7fffffff;
#pragma unroll
            for (int sg = 0; sg < 16; sg++) {
                ts += segS[sg * 32 + tid];
                ins2(segM1[sg * 32 + tid], segI1[sg * 32 + tid], a1, x1, a2, x2);
                ins2(segM2[sg * 32 + tid], segI2[sg * 32 + tid], a1, x1, a2, x2);
            }
            psum[tid * NFM + jb] = ts;
            pm1[tid * NFM + jb] = a1; pi1[tid * NFM + jb] = x1;
            pm2[tid * NFM + jb] = a2; pi2[tid * NFM + jb] = x2;
            const int tgt = x[tid * XROW + t + 1];
            const int loc = tgt - j0;
            if (loc >= 0 && loc < 64) lt[tid] = logits[loc * 33 + tid];
        }
    }

    if (cntF == nullptr) return;

    // ---- tail: last block performs fin ----
    __threadfence();
    __syncthreads();
    if (tid == 0) {
        const int old = atomicAdd(cntF, 1);
        sLastF = (old == NFM - 1) ? 1 : 0;
    }
    __syncthreads();
    if (!sLastF) return;
    __threadfence();

    {
        float* rS  = pool;          // [32][17]
        float* rM1 = pool + 544;
        float* rM2 = pool + 1088;
        int* rI1 = ipool;           // [32][17]
        int* rI2 = ipool + 544;
        const int b = tid >> 4, s = tid & 15;
        float sum = 0.f, m1 = -1e30f, m2 = -1e30f;
        int i1 = 0x7fffffff, i2 = 0x7fffffff;
        for (int q = s; q < NFM; q += 16) {
            sum += psum[b * NFM + q];
            ins2(pm1[b * NFM + q], pi1[b * NFM + q], m1, i1, m2, i2);
            ins2(pm2[b * NFM + q], pi2[b * NFM + q], m1, i1, m2, i2);
        }
        rS[b * 17 + s] = sum;
        rM1[b * 17 + s] = m1; rI1[b * 17 + s] = i1;
        rM2[b * 17 + s] = m2; rI2[b * 17 + s] = i2;
        __syncthreads();
        if (tid < 32) {
            float ts = 0.f, a1 = -1e30f, a2 = -1e30f;
            int x1 = 0x7fffffff, x2 = 0x7fffffff;
            for (int q = 0; q < 16; q++) {
                ts += rS[tid * 17 + q];
                ins2(rM1[tid * 17 + q], rI1[tid * 17 + q], a1, x1, a2, x2);
                ins2(rM2[tid * 17 + q], rI2[tid * 17 + q], a1, x1, a2, x2);
            }
            fsum2[tid] = ts; fm1a[tid] = a1; fm2a[tid] = a2;
            fi1a[tid] = x1; fi2a[tid] = x2; fwn[tid] = x1;
        }
    }
    __syncthreads();

    // guards: exact f32 recompute of contested top-2 per flagged b
    for (int bb = 0; bb < 32; bb++) {
        if (fm1a[bb] - fm2a[bb] < GAPT) {
            float a1 = 0.f, a2 = 0.f;
            if (tid < 256) {
                const float4 hv = ((const float4*)(h1f + (size_t)bb * HID))[tid];
                const float4 w1 = ((const float4*)(Wfc + (size_t)fi1a[bb] * HID))[tid];
                const float4 w2 = ((const float4*)(Wfc + (size_t)fi2a[bb] * HID))[tid];
                a1 = hv.x * w1.x + hv.y * w1.y + hv.z * w1.z + hv.w * w1.w;
                a2 = hv.x * w2.x + hv.y * w2.y + hv.z * w2.z + hv.w * w2.w;
            }
            float* sc = logits;
            sc[tid] = a1; sc[512 + tid] = a2;
            __syncthreads();
            for (int s2 = 128; s2 > 0; s2 >>= 1) {
                if (tid < s2) {
                    sc[tid] += sc[tid + s2];
                    sc[512 + tid] += sc[512 + tid + s2];
                }
                __syncthreads();
            }
            if (tid == 0) {
                const float l1 = sc[0]   + bfc[fi1a[bb]];
                const float l2 = sc[512] + bfc[fi2a[bb]];
                if (l2 > l1 || (l2 == l1 && fi2a[bb] < fi1a[bb])) fwn[bb] = fi2a[bb];
            }
            __syncthreads();
        }
    }

    if (tid < 32)
        out[(size_t)tid * TS + t] = expf(lt[tid]) / fsum2[tid];

    for (int u = tid; u < 32 * 256; u += 512) {
        const int b = u >> 8, q4 = u & 255;
        const float4 ev = ((const float4*)(emb + (size_t)fwn[b] * EMBD))[q4];
        ((float4*)(xcur + (size_t)b * EMBD))[q4] = ev;
        const size_t p0 = pidx_act(b, q4 * 4);
        const float e4[4] = {ev.x, ev.y, ev.z, ev.w};
#pragma unroll
        for (int q = 0; q < 4; q++) {
            const unsigned short hq = f2bu(e4[q]);
            xHi[p0 + q]  = hq;
            xMid[p0 + q] = f2bu(e4[q] - b2f(hq));
        }
    }
    if (tid == 0) { __threadfence(); *cntF = 0; }
}

// ================= R14-tier fallback kernels (f32 gates + separate fin) =====

__global__ __launch_bounds__(256) void k_init(
    const int* __restrict__ x, const float* __restrict__ emb,
    float* __restrict__ xcur, float* __restrict__ st)
{
    const int b = blockIdx.x, tid = threadIdx.x;
    float4 z = {0.f, 0.f, 0.f, 0.f};
#pragma unroll
    for (int q = 0; q < 4; q++)
        ((float4*)(st + (size_t)q * B * HID + (size_t)b * HID))[tid] = z;
    const int tok = x[b * XROW];
    ((float4*)(xcur + (size_t)b * EMBD))[tid] =
        ((const float4*)(emb + (size_t)tok * EMBD))[tid];
}

__global__ __launch_bounds__(512) void k_layer(
    const float* __restrict__ xin, const float* __restrict__ hin,
    const float* __restrict__ Wih, const float* __restrict__ Whh,
    float* __restrict__ gpart)
{
    __shared__ float4 sb4x[2048];
    const int tid = threadIdx.x;
    const int ww  = tid >> 6;
    const int lane = tid & 63;
    const int rs  = lane >> 2;
    const int kq  = lane & 3;
    const int jb  = blockIdx.x;
    const int ks  = blockIdx.y;
    const bool xpart = (ks < 4);
    const float* __restrict__ src = xpart ? xin : hin;
    const float* __restrict__ Wb  = xpart ? Wih : Whh;
    const int cchunk = (ks & 3) * 64;

#pragma unroll
    for (int e = 0; e < 4; e++) {
        const int fi = tid + e * 512;
        const int b = fi >> 6, off = fi & 63;
        sb4x[fi] = ((const float4*)(src + (size_t)b * 1024))[cchunk + off];
    }
    __syncthreads();

    const int j0 = jb * 128;
    const float4* W4 = (const float4*)Wb;
    const float4* wp[8];
#pragma unroll
    for (int jj = 0; jj < 8; jj++)
        wp[jj] = W4 + (size_t)(j0 + rs * 8 + jj) * 256 + cchunk;

    float acc[8][4];
#pragma unroll
    for (int jj = 0; jj < 8; jj++)
#pragma unroll
        for (int bl = 0; bl < 4; bl++) acc[jj][bl] = 0.f;

#pragma unroll 4
    for (int s = 0; s < 16; s++) {
        const int col = s * 4 + kq;
        float4 w[8];
#pragma unroll
        for (int jj = 0; jj < 8; jj++) w[jj] = wp[jj][col];
#pragma unroll
        for (int bl = 0; bl < 4; bl++) {
            const float4 xv = sb4x[(ww * 4 + bl) * 64 + col];
#pragma unroll
            for (int jj = 0; jj < 8; jj++) FMA4(acc[jj][bl], w[jj], xv);
        }
    }

#pragma unroll
    for (int jj = 0; jj < 8; jj++)
#pragma unroll
        for (int bl = 0; bl < 4; bl++) {
            acc[jj][bl] += __shfl_xor(acc[jj][bl], 1);
            acc[jj][bl] += __shfl_xor(acc[jj][bl], 2);
        }

#pragma unroll
    for (int q = 0; q < 2; q++) {
        const int jjw = 2 * kq + q;
        const int r = j0 + rs * 8 + jjw;
#pragma unroll
        for (int bl = 0; bl < 4; bl++) {
            const int b = ww * 4 + bl;
            float v = acc[0][bl];
#pragma unroll
            for (int jj = 1; jj < 8; jj++)
                if (jjw == jj) v = acc[jj][bl];
            gpart[((size_t)ks * B + b) * G + r] = v;
        }
    }
}

__global__ __launch_bounds__(256) void k_act(
    const float* __restrict__ part, const float* __restrict__ bih,
    const float* __restrict__ bhh, float* __restrict__ c, float* __restrict__ h,
    unsigned short* __restrict__ hbr)
{
    const int idx = blockIdx.x * 256 + threadIdx.x;
    const int b = idx >> 10, jh = idx & 1023;
    float gi = bih[jh]        + bhh[jh];
    float gf = bih[jh + 1024] + bhh[jh + 1024];
    float gg = bih[jh + 2048] + bhh[jh + 2048];
    float go = bih[jh + 3072] + bhh[jh + 3072];
#pragma unroll
    for (int ks = 0; ks < KSL; ks++) {
        const float* p = part + ((size_t)ks * B + b) * G;
        gi += p[jh]; gf += p[jh + 1024]; gg += p[jh + 2048]; go += p[jh + 3072];
    }
    const float i = 1.f / (1.f + expf(-gi));
    const float f = 1.f / (1.f + expf(-gf));
    const float g = tanhf(gg);
    const float o = 1.f / (1.f + expf(-go));
    const float cn = f * c[idx] + i * g;
    c[idx] = cn;
    const float hv = o * tanhf(cn);
    h[idx] = hv;
    hbr[pidx_act(b, jh)] = f2bu(hv);
}

__global__ __launch_bounds__(512) void k_fin2(
    const float* __restrict__ psum, const float* __restrict__ pm1,
    const float* __restrict__ pm2, const int* __restrict__ pi1,
    const int* __restrict__ pi2, const float* __restrict__ lt,
    const float* __restrict__ h1, const float* __restrict__ Wfc,
    const float* __restrict__ bfc, const float* __restrict__ emb,
    float* __restrict__ xcur, float* __restrict__ out, int t)
{
    __shared__ float ss[512], sm1[512], sm2[512];
    __shared__ int si1[512], si2[512];
    __shared__ int sW, sA, sB2, sNeed;
    const int b = blockIdx.x, tid = threadIdx.x;

    const bool v = (tid < NFM);
    ss[tid]  = v ? psum[b * NFM + tid] : 0.f;
    sm1[tid] = v ? pm1[b * NFM + tid] : -1e30f;
    sm2[tid] = v ? pm2[b * NFM + tid] : -1e30f;
    si1[tid] = v ? pi1[b * NFM + tid] : 0x7fffffff;
    si2[tid] = v ? pi2[b * NFM + tid] : 0x7fffffff;
    __syncthreads();
    for (int s = 256; s > 0; s >>= 1) {
        if (tid < s) {
            ss[tid] += ss[tid + s];
            float a1 = sm1[tid], a2 = sm2[tid];
            int x1 = si1[tid], x2 = si2[tid];
            ins2(sm1[tid + s], si1[tid + s], a1, x1, a2, x2);
            ins2(sm2[tid + s], si2[tid + s], a1, x1, a2, x2);
            sm1[tid] = a1; si1[tid] = x1; sm2[tid] = a2; si2[tid] = x2;
        }
        __syncthreads();
    }
    if (tid == 0) {
        out[(size_t)b * TS + t] = expf(lt[b]) / ss[0];
        sW = si1[0]; sA = si1[0]; sB2 = si2[0];
        sNeed = (sm1[0] - sm2[0] < GAPT) ? 1 : 0;
    }
    __syncthreads();

    if (sNeed) {
        const int ia = sA, ib = sB2;
        float a1 = 0.f, a2 = 0.f;
        if (tid < 256) {
            const float4 hv = ((const float4*)(h1 + (size_t)b * HID))[tid];
            const float4 w1 = ((const float4*)(Wfc + (size_t)ia * HID))[tid];
            const float4 w2 = ((const float4*)(Wfc + (size_t)ib * HID))[tid];
            a1 = hv.x * w1.x + hv.y * w1.y + hv.z * w1.z + hv.w * w1.w;
            a2 = hv.x * w2.x + hv.y * w2.y + hv.z * w2.z + hv.w * w2.w;
        }
        __syncthreads();
        sm1[tid] = a1; sm2[tid] = a2;
        __syncthreads();
        for (int s = 128; s > 0; s >>= 1) {
            if (tid < s) { sm1[tid] += sm1[tid + s]; sm2[tid] += sm2[tid + s]; }
            __syncthreads();
        }
        if (tid == 0) {
            const float l1 = sm1[0] + bfc[ia];
            const float l2 = sm2[0] + bfc[ib];
            if (l2 > l1 || (l2 == l1 && ib < ia)) sW = ib;
        }
        __syncthreads();
    }
    if (tid < 256)
        ((float4*)(xcur + (size_t)b * EMBD))[tid] =
            ((const float4*)(emb + (size_t)sW * EMBD))[tid];
}

// ================= launch =================

extern "C" void kernel_launch(void* const* d_in, const int* in_sizes, int n_in,
                              void* d_out, int out_size, void* d_ws, size_t ws_size,
                              hipStream_t stream)
{
    const int*   x   = (const int*)  d_in[0];
    const float* emb = (const float*)d_in[1];
    const float* Wih = (const float*)d_in[2];
    const float* Whh = (const float*)d_in[3];
    const float* bih = (const float*)d_in[4];
    const float* bhh = (const float*)d_in[5];
    const float* Wfc = (const float*)d_in[6];
    const float* bfc = (const float*)d_in[7];
    float* out = (float*)d_out;
    float* ws = (float*)d_ws;

    // layout (float slots)
    const size_t o_xcur = 0;
    const size_t o_st   = 32768;
    const size_t o_gp   = 163840;
    const size_t o_ps   = 1212416;
    const size_t o_m1   = 1228416;
    const size_t o_m2   = 1244416;
    const size_t o_i1   = 1260416;
    const size_t o_i2   = 1276416;
    const size_t o_lt   = 1292416;
    const size_t o_hbr  = 1292448;
    const size_t o_whr  = 1308832;
    const size_t NEED_FC = (size_t)(1308832 + 16384000) * 4;
    const size_t o_pl   = 17692832;
    const size_t o_gw   = o_pl + 6 * 8192;
    const size_t o_cnt  = o_gw + 16777216;
    const size_t NEED_ALL = (o_cnt + 128) * 4;

    float* xcur = ws + o_xcur;
    float* h0 = ws + o_st, *h1 = h0 + 32768, *c0 = h1 + 32768, *c1 = c0 + 32768;
    float* gpart = ws + o_gp;
    float* psum = ws + o_ps;
    float* pm1  = ws + o_m1;
    float* pm2  = ws + o_m2;
    int*   pi1  = (int*)(ws + o_i1);
    int*   pi2  = (int*)(ws + o_i2);
    float* lt   = ws + o_lt;
    unsigned short* hbr = (unsigned short*)(ws + o_hbr);
    unsigned short* Whr = (unsigned short*)(ws + o_whr);
    unsigned short* xHi   = (unsigned short*)(ws + o_pl);
    unsigned short* xMid  = xHi + 32768;
    unsigned short* h0Hi  = xMid + 32768;
    unsigned short* h0Mid = h0Hi + 32768;
    unsigned short* h1Hi  = h0Mid + 32768;
    unsigned short* h1Mid = h1Hi + 32768;
    unsigned short* Gw = (unsigned short*)(ws + o_gw);
    int* cnt = (int*)(ws + o_cnt);   // [0..31]=L0, [32..63]=L1, [64]=fc
    unsigned short* gw_p[2][2][2];
    for (int L = 0; L < 2; L++)
        for (int m = 0; m < 2; m++)
            for (int p = 0; p < 2; p++)
                gw_p[L][m][p] = Gw + (((size_t)L * 2 + m) * 2 + p) * GWM;

    const size_t G4 = (size_t)G;
    const bool fc_ok  = (ws_size >= NEED_FC);
    const bool all_ok = (ws_size >= NEED_ALL);

    if (fc_ok)
        k_conv<<<4096, 256, 0, stream>>>(Wfc, Whr);

    if (all_ok) {
        k_conv_g<<<2048, 256, 0, stream>>>(Wih,             gw_p[0][0][0], gw_p[0][0][1]);
        k_conv_g<<<2048, 256, 0, stream>>>(Whh,             gw_p[0][1][0], gw_p[0][1][1]);
        k_conv_g<<<2048, 256, 0, stream>>>(Wih + G4 * EMBD, gw_p[1][0][0], gw_p[1][0][1]);
        k_conv_g<<<2048, 256, 0, stream>>>(Whh + G4 * HID,  gw_p[1][1][0], gw_p[1][1][1]);
        k_init_m<<<B, 256, 0, stream>>>(x, emb, xcur, ws + o_st,
                                        xHi, xMid, h0Hi, h0Mid, h1Hi, h1Mid, cnt);
        for (int t = 0; t < TS; t++) {
            k_layer_mf<<<dim3(32, KSL), 512, 0, stream>>>(
                gw_p[0][0][0], gw_p[0][0][1], gw_p[0][1][0], gw_p[0][1][1],
                xHi, xMid, h0Hi, h0Mid, gpart, bih, bhh, c0,
                h0Hi, h0Mid, nullptr, cnt);
            k_layer_mf<<<dim3(32, KSL), 512, 0, stream>>>(
                gw_p[1][0][0], gw_p[1][0][1], gw_p[1][1][0], gw_p[1][1][1],
                h0Hi, h0Mid, h1Hi, h1Mid, gpart, bih + G, bhh + G, c1,
                h1Hi, h1Mid, h1, cnt + 32);
            k_fc_mfma<<<NFM, 512, 0, stream>>>(Whr, h1Hi, bfc, x, t,
                                               psum, pm1, pm2, pi1, pi2, lt,
                                               h1, Wfc, emb, xcur, xHi, xMid,
                                               out, cnt + 64);
        }
        return;
    }

    // ---- R14 tier: f32 gates + MFMA FC + separate fin ----
    k_init<<<B, 256, 0, stream>>>(x, emb, xcur, ws + o_st);
    for (int t = 0; t < TS; t++) {
        k_layer<<<dim3(32, KSL), 512, 0, stream>>>(xcur, h0, Wih, Whh, gpart);
        k_act<<<128, 256, 0, stream>>>(gpart, bih, bhh, c0, h0, hbr);
        k_layer<<<dim3(32, KSL), 512, 0, stream>>>(h0, h1, Wih + G4 * EMBD,
                                                   Whh + G4 * HID, gpart);
        k_act<<<128, 256, 0, stream>>>(gpart, bih + G, bhh + G, c1, h1, hbr);
        k_fc_mfma<<<NFM, 512, 0, stream>>>(Whr, hbr, bfc, x, t,
                                           psum, pm1, pm2, pi1, pi2, lt,
                                           h1, Wfc, emb, xcur,
                                           (unsigned short*)(ws + o_hbr),
                                           (unsigned short*)(ws + o_hbr),
                                           out, nullptr);
        k_fin2<<<B, 512, 0, stream>>>(psum, pm1, pm2, pi1, pi2, lt,
                                      h1, Wfc, bfc, emb, xcur, out, t);
    }
}

// Round 17
// 7252.450 us; speedup vs baseline: 5.4455x; 5.4455x over previous
//
#include <hip/hip_runtime.h>
#include <hip/hip_bf16.h>
#include <math.h>

#define B    32
#define EMBD 1024
#define HID  1024
#define G    4096
#define V    32000
#define TS   128
#define XROW (TS + 1)
#define KSL  8
#define NFM  500
#define GAPT 2e-3f
#define GWM  (4096 * 1024)

typedef short bf16x8 __attribute__((ext_vector_type(8)));
typedef float f32x4  __attribute__((ext_vector_type(4)));

#define FMA4(acc, W_, V_) \
  acc = fmaf((W_).x,(V_).x, fmaf((W_).y,(V_).y, fmaf((W_).z,(V_).z, fmaf((W_).w,(V_).w,(acc)))))

__device__ __forceinline__ unsigned short f2bu(float x) {
    __hip_bfloat16 b = __float2bfloat16(x);
    return *reinterpret_cast<unsigned short*>(&b);
}
__device__ __forceinline__ float b2f(unsigned short u) {
    union { unsigned int v; float f; } c; c.v = ((unsigned int)u) << 16; return c.f;
}
__device__ __forceinline__ void ins2(float m, int i, float& m1, int& i1,
                                     float& m2, int& i2) {
    if (m > m1 || (m == m1 && i < i1)) { m2 = m1; i2 = i1; m1 = m; i1 = i; }
    else if (m > m2 || (m == m2 && i < i2)) { m2 = m; i2 = i; }
}
__device__ __forceinline__ size_t pidx_act(int b, int jh) {
    const int kb = jh >> 5, kslot = (jh >> 3) & 3, e = jh & 7;
    const int lane = kslot * 16 + (b & 15);
    return ((((size_t)(b >> 4)) * 32 + kb) * 64 + lane) * 8 + e;
}

// ---------------- FC weight bf16 fragment-major reorder (R14-verified) -----
__global__ __launch_bounds__(256) void k_conv(
    const float* __restrict__ W, unsigned short* __restrict__ out)
{
    const int ngrp = V * HID / 8;
    for (int o = blockIdx.x * 256 + threadIdx.x; o < ngrp; o += gridDim.x * 256) {
        const int lane = o & 63, kb = (o >> 6) & 31, tile = o >> 11;
        const int row = tile * 16 + (lane & 15);
        const int k0  = kb * 32 + (lane >> 4) * 8;
        const float4 v0 = *(const float4*)(W + (size_t)row * 1024 + k0);
        const float4 v1 = *(const float4*)(W + (size_t)row * 1024 + k0 + 4);
        ushort4 a, b;
        a.x = f2bu(v0.x); a.y = f2bu(v0.y); a.z = f2bu(v0.z); a.w = f2bu(v0.w);
        b.x = f2bu(v1.x); b.y = f2bu(v1.y); b.z = f2bu(v1.z); b.w = f2bu(v1.w);
        ((ushort4*)out)[o * 2]     = a;
        ((ushort4*)out)[o * 2 + 1] = b;
    }
}

// ---------------- gate weights: concat-K, act-grouped tiles ---------------
// layout [tile 0..255][kbg 0..63][lane][8]; tile jq holds rows gate*1024 +
// jq*4 + jr with in-tile row = gate*4+jr; kbg<32 = Wih, kbg>=32 = Whh.
__global__ __launch_bounds__(256) void k_conv_g2(
    const float* __restrict__ Wih, const float* __restrict__ Whh,
    unsigned short* __restrict__ hi, unsigned short* __restrict__ mid)
{
    const int ngrp = 256 * 64 * 64;   // 1,048,576 groups of 8
    for (int o = blockIdx.x * 256 + threadIdx.x; o < ngrp; o += gridDim.x * 256) {
        const int lane = o & 63, kbg = (o >> 6) & 63, tile = o >> 12;
        const int ir = lane & 15;
        const int gate = ir >> 2, jr = ir & 3;
        const int row = gate * 1024 + tile * 4 + jr;
        const bool xp = (kbg < 32);
        const float* src = xp ? Wih : Whh;
        const int kbl = xp ? kbg : (kbg - 32);
        const int k0 = kbl * 32 + (lane >> 4) * 8;
#pragma unroll
        for (int q = 0; q < 2; q++) {
            const float4 v = *(const float4*)(src + (size_t)row * 1024 + k0 + q * 4);
            ushort4 h, m;
            h.x = f2bu(v.x); m.x = f2bu(v.x - b2f(h.x));
            h.y = f2bu(v.y); m.y = f2bu(v.y - b2f(h.y));
            h.z = f2bu(v.z); m.z = f2bu(v.z - b2f(h.z));
            h.w = f2bu(v.w); m.w = f2bu(v.w - b2f(h.w));
            ((ushort4*)hi)[o * 2 + q]  = h;
            ((ushort4*)mid)[o * 2 + q] = m;
        }
    }
}

// ---------------- init (mfma tier): states=0, planes ----------------
__global__ __launch_bounds__(256) void k_init_m(
    const int* __restrict__ x, const float* __restrict__ emb,
    float* __restrict__ xcur, float* __restrict__ st,
    unsigned short* __restrict__ xHi, unsigned short* __restrict__ xMid,
    unsigned short* __restrict__ h0Hi, unsigned short* __restrict__ h0Mid,
    unsigned short* __restrict__ h1Hi, unsigned short* __restrict__ h1Mid)
{
    const int b = blockIdx.x, tid = threadIdx.x;
    float4 z = {0.f, 0.f, 0.f, 0.f};
#pragma unroll
    for (int q = 0; q < 4; q++)
        ((float4*)(st + (size_t)q * B * HID + (size_t)b * HID))[tid] = z;
    const int tok = x[b * XROW];
    const float4 ev = ((const float4*)(emb + (size_t)tok * EMBD))[tid];
    ((float4*)(xcur + (size_t)b * EMBD))[tid] = ev;
    const int jh0 = tid * 4;
    const size_t p0 = pidx_act(b, jh0);
    const float e4[4] = {ev.x, ev.y, ev.z, ev.w};
#pragma unroll
    for (int q = 0; q < 4; q++) {
        const unsigned short h = f2bu(e4[q]);
        xHi[p0 + q]  = h;
        xMid[p0 + q] = f2bu(e4[q] - b2f(h));
        h0Hi[p0 + q] = 0; h0Mid[p0 + q] = 0;
        h1Hi[p0 + q] = 0; h1Mid[p0 + q] = 0;
    }
}

// ---------------- fused gates GEMM + in-block act ---------------------------
// grid 256 (jq = 4 jh each), block 512 = 8 waves (k-split over 2048 concat).
// Wave wv: one 16-row tile (4 gates x 4 jh) x 8 kbg chunk. LDS 8-way reduce,
// then act + c update + h planes (+ optional f32 h), all in-block.
__global__ __launch_bounds__(512) void k_layer_f(
    const unsigned short* __restrict__ Ahi, const unsigned short* __restrict__ Amid,
    const unsigned short* __restrict__ xHi, const unsigned short* __restrict__ xMid,
    const unsigned short* __restrict__ hHi, const unsigned short* __restrict__ hMid,
    const float* __restrict__ bih, const float* __restrict__ bhh,
    float* __restrict__ c2,
    unsigned short* __restrict__ oHi, unsigned short* __restrict__ oMid,
    float* __restrict__ h_f32)
{
    __shared__ float red[8 * 16 * 33];      // 16.5 KB
    const int tid = threadIdx.x;
    const int wv  = tid >> 6;               // 0..7 (k-chunk)
    const int lane = tid & 63;
    const int jq  = blockIdx.x;             // 0..255
    const bool xp = (wv < 4);
    const unsigned short* Bh = xp ? xHi : hHi;
    const unsigned short* Bm = xp ? xMid : hMid;
    const int kbl0 = xp ? (wv * 8) : ((wv - 4) * 8);

    f32x4 acc0 = {0.f, 0.f, 0.f, 0.f};
    f32x4 acc1 = {0.f, 0.f, 0.f, 0.f};

#pragma unroll 4
    for (int i = 0; i < 8; i++) {
        const int kbg = wv * 8 + i;
        const int kbl = kbl0 + i;
        const size_t aoff = (((size_t)jq * 64 + kbg) * 64 + lane) * 8;
        const bf16x8 Avh = *(const bf16x8*)(Ahi + aoff);
        const bf16x8 Avm = *(const bf16x8*)(Amid + aoff);
        const size_t b0off = (((size_t)kbl) * 64 + lane) * 8;
        const size_t b1off = (((size_t)(32 + kbl)) * 64 + lane) * 8;
        const bf16x8 B0h = *(const bf16x8*)(Bh + b0off);
        const bf16x8 B0m = *(const bf16x8*)(Bm + b0off);
        const bf16x8 B1h = *(const bf16x8*)(Bh + b1off);
        const bf16x8 B1m = *(const bf16x8*)(Bm + b1off);
        acc0 = __builtin_amdgcn_mfma_f32_16x16x32_bf16(Avh, B0h, acc0, 0, 0, 0);
        acc1 = __builtin_amdgcn_mfma_f32_16x16x32_bf16(Avh, B1h, acc1, 0, 0, 0);
        acc0 = __builtin_amdgcn_mfma_f32_16x16x32_bf16(Avh, B0m, acc0, 0, 0, 0);
        acc1 = __builtin_amdgcn_mfma_f32_16x16x32_bf16(Avh, B1m, acc1, 0, 0, 0);
        acc0 = __builtin_amdgcn_mfma_f32_16x16x32_bf16(Avm, B0h, acc0, 0, 0, 0);
        acc1 = __builtin_amdgcn_mfma_f32_16x16x32_bf16(Avm, B1h, acc1, 0, 0, 0);
    }

    // D: in-tile row=(lane>>4)*4+r, col=lane&15 (batch within half)
    {
        const int bcol = lane & 15;
#pragma unroll
        for (int r = 0; r < 4; r++) {
            const int rd = (lane >> 4) * 4 + r;
            red[(wv * 16 + rd) * 33 + bcol]      = acc0[r];
            red[(wv * 16 + rd) * 33 + 16 + bcol] = acc1[r];
        }
    }
    __syncthreads();

    if (tid < 128) {
        const int jr = tid >> 5, b = tid & 31;
        const int jh = jq * 4 + jr;
        float gs[4];
#pragma unroll
        for (int g = 0; g < 4; g++) {
            const int rd = g * 4 + jr;
            float v = 0.f;
#pragma unroll
            for (int w = 0; w < 8; w++)
                v += red[(w * 16 + rd) * 33 + b];
            gs[g] = v + bih[g * 1024 + jh] + bhh[g * 1024 + jh];
        }
        const float i = 1.f / (1.f + expf(-gs[0]));
        const float f = 1.f / (1.f + expf(-gs[1]));
        const float g = tanhf(gs[2]);
        const float o = 1.f / (1.f + expf(-gs[3]));
        const int ci = jh * 32 + b;
        const float cn = f * c2[ci] + i * g;
        c2[ci] = cn;
        const float hv = o * tanhf(cn);
        if (h_f32) h_f32[(size_t)b * HID + jh] = hv;
        const size_t p = pidx_act(b, jh);
        const unsigned short uh = f2bu(hv);
        oHi[p]  = uh;
        oMid[p] = f2bu(hv - b2f(uh));
    }
}

// ---------------- MFMA FC (R14/R15-verified) --------------------------------
__global__ __launch_bounds__(512, 4) void k_fc_mfma(
    const unsigned short* __restrict__ Whr, const unsigned short* __restrict__ hbr,
    const float* __restrict__ bfc, const int* __restrict__ x, int t,
    float* __restrict__ psum, float* __restrict__ pm1, float* __restrict__ pm2,
    int* __restrict__ pi1, int* __restrict__ pi2, float* __restrict__ lt)
{
    __shared__ float logits[64 * 33];
    __shared__ float segS[16 * 32], segM1[16 * 32], segM2[16 * 32];
    __shared__ int   segI1[16 * 32], segI2[16 * 32];

    const int tid = threadIdx.x;
    const int wv  = tid >> 6;
    const int kh  = wv >> 2;
    const int rg  = wv & 3;
    const int lane = tid & 63;
    const int jb  = blockIdx.x;
    const int j0  = jb * 64;

    const unsigned short* Ab = Whr + ((size_t)(jb * 4 + rg) * 32 * 64) * 8;

    f32x4 acc0 = {0.f, 0.f, 0.f, 0.f};
    f32x4 acc1 = {0.f, 0.f, 0.f, 0.f};

#pragma unroll 4
    for (int i = 0; i < 16; i++) {
        const int kb = kh * 16 + i;
        const bf16x8 Av = *(const bf16x8*)(Ab + ((size_t)kb * 64 + lane) * 8);
        const bf16x8 B0 = *(const bf16x8*)(hbr + (((size_t)kb) * 64 + lane) * 8);
        const bf16x8 B1 = *(const bf16x8*)(hbr + (((size_t)(32 + kb)) * 64 + lane) * 8);
        acc0 = __builtin_amdgcn_mfma_f32_16x16x32_bf16(Av, B0, acc0, 0, 0, 0);
        acc1 = __builtin_amdgcn_mfma_f32_16x16x32_bf16(Av, B1, acc1, 0, 0, 0);
    }

    const int rbase = rg * 16 + (lane >> 4) * 4;
    const int bcol  = lane & 15;
    if (kh == 0) {
#pragma unroll
        for (int r = 0; r < 4; r++) {
            const int rw = rbase + r;
            logits[rw * 33 + bcol]      = acc0[r] + bfc[j0 + rw];
            logits[rw * 33 + 16 + bcol] = acc1[r];
        }
    }
    __syncthreads();
    if (kh == 1) {
#pragma unroll
        for (int r = 0; r < 4; r++) {
            const int rw = rbase + r;
            logits[rw * 33 + bcol]      += acc0[r];
            logits[rw * 33 + 16 + bcol] += acc1[r] + bfc[j0 + rw];
        }
    }
    __syncthreads();

    {
        const int b = tid & 31, seg = tid >> 5;
        float ls = 0.f, m1 = -1e30f, m2 = -1e30f;
        int i1 = 0x7fffffff, i2 = 0x7fffffff;
#pragma unroll
        for (int i = 0; i < 4; i++) {
            const int rw = seg * 4 + i;
            const float l = logits[rw * 33 + b];
            ls += expf(l);
            ins2(l, j0 + rw, m1, i1, m2, i2);
        }
        segS[seg * 32 + b] = ls;
        segM1[seg * 32 + b] = m1; segI1[seg * 32 + b] = i1;
        segM2[seg * 32 + b] = m2; segI2[seg * 32 + b] = i2;
    }
    __syncthreads();
    if (tid < 32) {
        const int b = tid;
        float ts = 0.f, m1 = -1e30f, m2 = -1e30f;
        int i1 = 0x7fffffff, i2 = 0x7fffffff;
#pragma unroll
        for (int seg = 0; seg < 16; seg++) {
            ts += segS[seg * 32 + b];
            ins2(segM1[seg * 32 + b], segI1[seg * 32 + b], m1, i1, m2, i2);
            ins2(segM2[seg * 32 + b], segI2[seg * 32 + b], m1, i1, m2, i2);
        }
        psum[b * NFM + jb] = ts;
        pm1[b * NFM + jb] = m1; pi1[b * NFM + jb] = i1;
        pm2[b * NFM + jb] = m2; pi2[b * NFM + jb] = i2;
        const int tgt = x[b * XROW + t + 1];
        const int loc = tgt - j0;
        if (loc >= 0 && loc < 64) lt[b] = logits[loc * 33 + b];
    }
}

// ---------------- finalize + guard + next embedding (+x planes) ------------
__global__ __launch_bounds__(512) void k_fin2(
    const float* __restrict__ psum, const float* __restrict__ pm1,
    const float* __restrict__ pm2, const int* __restrict__ pi1,
    const int* __restrict__ pi2, const float* __restrict__ lt,
    const float* __restrict__ h1, const float* __restrict__ Wfc,
    const float* __restrict__ bfc, const float* __restrict__ emb,
    float* __restrict__ xcur, unsigned short* __restrict__ xHi,
    unsigned short* __restrict__ xMid, float* __restrict__ out, int t)
{
    __shared__ float ss[512], sm1[512], sm2[512];
    __shared__ int si1[512], si2[512];
    __shared__ int sW, sA, sB2, sNeed;
    const int b = blockIdx.x, tid = threadIdx.x;

    const bool v = (tid < NFM);
    ss[tid]  = v ? psum[b * NFM + tid] : 0.f;
    sm1[tid] = v ? pm1[b * NFM + tid] : -1e30f;
    sm2[tid] = v ? pm2[b * NFM + tid] : -1e30f;
    si1[tid] = v ? pi1[b * NFM + tid] : 0x7fffffff;
    si2[tid] = v ? pi2[b * NFM + tid] : 0x7fffffff;
    __syncthreads();
    for (int s = 256; s > 0; s >>= 1) {
        if (tid < s) {
            ss[tid] += ss[tid + s];
            float a1 = sm1[tid], a2 = sm2[tid];
            int x1 = si1[tid], x2 = si2[tid];
            ins2(sm1[tid + s], si1[tid + s], a1, x1, a2, x2);
            ins2(sm2[tid + s], si2[tid + s], a1, x1, a2, x2);
            sm1[tid] = a1; si1[tid] = x1; sm2[tid] = a2; si2[tid] = x2;
        }
        __syncthreads();
    }
    if (tid == 0) {
        out[(size_t)b * TS + t] = expf(lt[b]) / ss[0];
        sW = si1[0]; sA = si1[0]; sB2 = si2[0];
        sNeed = (sm1[0] - sm2[0] < GAPT) ? 1 : 0;
    }
    __syncthreads();

    if (sNeed) {
        const int ia = sA, ib = sB2;
        float a1 = 0.f, a2 = 0.f;
        if (tid < 256) {
            const float4 hv = ((const float4*)(h1 + (size_t)b * HID))[tid];
            const float4 w1 = ((const float4*)(Wfc + (size_t)ia * HID))[tid];
            const float4 w2 = ((const float4*)(Wfc + (size_t)ib * HID))[tid];
            a1 = hv.x * w1.x + hv.y * w1.y + hv.z * w1.z + hv.w * w1.w;
            a2 = hv.x * w2.x + hv.y * w2.y + hv.z * w2.z + hv.w * w2.w;
        }
        __syncthreads();
        sm1[tid] = a1; sm2[tid] = a2;
        __syncthreads();
        for (int s = 128; s > 0; s >>= 1) {
            if (tid < s) { sm1[tid] += sm1[tid + s]; sm2[tid] += sm2[tid + s]; }
            __syncthreads();
        }
        if (tid == 0) {
            const float l1 = sm1[0] + bfc[ia];
            const float l2 = sm2[0] + bfc[ib];
            if (l2 > l1 || (l2 == l1 && ib < ia)) sW = ib;
        }
        __syncthreads();
    }
    if (tid < 256) {
        const float4 ev = ((const float4*)(emb + (size_t)sW * EMBD))[tid];
        ((float4*)(xcur + (size_t)b * EMBD))[tid] = ev;
        const int jh0 = tid * 4;
        const size_t p0 = pidx_act(b, jh0);
        const float e4[4] = {ev.x, ev.y, ev.z, ev.w};
#pragma unroll
        for (int q = 0; q < 4; q++) {
            const unsigned short h = f2bu(e4[q]);
            xHi[p0 + q]  = h;
            xMid[p0 + q] = f2bu(e4[q] - b2f(h));
        }
    }
}

// ================= R14-tier fallback kernels (f32 gates) =================

__global__ __launch_bounds__(256) void k_init(
    const int* __restrict__ x, const float* __restrict__ emb,
    float* __restrict__ xcur, float* __restrict__ st)
{
    const int b = blockIdx.x, tid = threadIdx.x;
    float4 z = {0.f, 0.f, 0.f, 0.f};
#pragma unroll
    for (int q = 0; q < 4; q++)
        ((float4*)(st + (size_t)q * B * HID + (size_t)b * HID))[tid] = z;
    const int tok = x[b * XROW];
    ((float4*)(xcur + (size_t)b * EMBD))[tid] =
        ((const float4*)(emb + (size_t)tok * EMBD))[tid];
}

__global__ __launch_bounds__(512) void k_layer(
    const float* __restrict__ xin, const float* __restrict__ hin,
    const float* __restrict__ Wih, const float* __restrict__ Whh,
    float* __restrict__ gpart)
{
    __shared__ float4 sb4x[2048];
    const int tid = threadIdx.x;
    const int ww  = tid >> 6;
    const int lane = tid & 63;
    const int rs  = lane >> 2;
    const int kq  = lane & 3;
    const int jb  = blockIdx.x;
    const int ks  = blockIdx.y;
    const bool xpart = (ks < 4);
    const float* __restrict__ src = xpart ? xin : hin;
    const float* __restrict__ Wb  = xpart ? Wih : Whh;
    const int cchunk = (ks & 3) * 64;

#pragma unroll
    for (int e = 0; e < 4; e++) {
        const int fi = tid + e * 512;
        const int b = fi >> 6, off = fi & 63;
        sb4x[fi] = ((const float4*)(src + (size_t)b * 1024))[cchunk + off];
    }
    __syncthreads();

    const int j0 = jb * 128;
    const float4* W4 = (const float4*)Wb;
    const float4* wp[8];
#pragma unroll
    for (int jj = 0; jj < 8; jj++)
        wp[jj] = W4 + (size_t)(j0 + rs * 8 + jj) * 256 + cchunk;

    float acc[8][4];
#pragma unroll
    for (int jj = 0; jj < 8; jj++)
#pragma unroll
        for (int bl = 0; bl < 4; bl++) acc[jj][bl] = 0.f;

#pragma unroll 4
    for (int s = 0; s < 16; s++) {
        const int col = s * 4 + kq;
        float4 w[8];
#pragma unroll
        for (int jj = 0; jj < 8; jj++) w[jj] = wp[jj][col];
#pragma unroll
        for (int bl = 0; bl < 4; bl++) {
            const float4 xv = sb4x[(ww * 4 + bl) * 64 + col];
#pragma unroll
            for (int jj = 0; jj < 8; jj++) FMA4(acc[jj][bl], w[jj], xv);
        }
    }

#pragma unroll
    for (int jj = 0; jj < 8; jj++)
#pragma unroll
        for (int bl = 0; bl < 4; bl++) {
            acc[jj][bl] += __shfl_xor(acc[jj][bl], 1);
            acc[jj][bl] += __shfl_xor(acc[jj][bl], 2);
        }

#pragma unroll
    for (int q = 0; q < 2; q++) {
        const int jjw = 2 * kq + q;
        const int r = j0 + rs * 8 + jjw;
#pragma unroll
        for (int bl = 0; bl < 4; bl++) {
            const int b = ww * 4 + bl;
            float v = acc[0][bl];
#pragma unroll
            for (int jj = 1; jj < 8; jj++)
                if (jjw == jj) v = acc[jj][bl];
            gpart[((size_t)ks * B + b) * G + r] = v;
        }
    }
}

__global__ __launch_bounds__(256) void k_act(
    const float* __restrict__ part, const float* __restrict__ bih,
    const float* __restrict__ bhh, float* __restrict__ c, float* __restrict__ h,
    unsigned short* __restrict__ hbr)
{
    const int idx = blockIdx.x * 256 + threadIdx.x;
    const int b = idx >> 10, jh = idx & 1023;
    float gi = bih[jh]        + bhh[jh];
    float gf = bih[jh + 1024] + bhh[jh + 1024];
    float gg = bih[jh + 2048] + bhh[jh + 2048];
    float go = bih[jh + 3072] + bhh[jh + 3072];
#pragma unroll
    for (int ks = 0; ks < KSL; ks++) {
        const float* p = part + ((size_t)ks * B + b) * G;
        gi += p[jh]; gf += p[jh + 1024]; gg += p[jh + 2048]; go += p[jh + 3072];
    }
    const float i = 1.f / (1.f + expf(-gi));
    const float f = 1.f / (1.f + expf(-gf));
    const float g = tanhf(gg);
    const float o = 1.f / (1.f + expf(-go));
    const float cn = f * c[idx] + i * g;
    c[idx] = cn;
    const float hv = o * tanhf(cn);
    h[idx] = hv;
    hbr[pidx_act(b, jh)] = f2bu(hv);
}

// ================= launch =================

extern "C" void kernel_launch(void* const* d_in, const int* in_sizes, int n_in,
                              void* d_out, int out_size, void* d_ws, size_t ws_size,
                              hipStream_t stream)
{
    const int*   x   = (const int*)  d_in[0];
    const float* emb = (const float*)d_in[1];
    const float* Wih = (const float*)d_in[2];
    const float* Whh = (const float*)d_in[3];
    const float* bih = (const float*)d_in[4];
    const float* bhh = (const float*)d_in[5];
    const float* Wfc = (const float*)d_in[6];
    const float* bfc = (const float*)d_in[7];
    float* out = (float*)d_out;
    float* ws = (float*)d_ws;

    // layout (float slots) — R15-compatible
    const size_t o_xcur = 0;
    const size_t o_st   = 32768;
    const size_t o_gp   = 163840;
    const size_t o_ps   = 1212416;
    const size_t o_m1   = 1228416;
    const size_t o_m2   = 1244416;
    const size_t o_i1   = 1260416;
    const size_t o_i2   = 1276416;
    const size_t o_lt   = 1292416;
    const size_t o_hbr  = 1292448;
    const size_t o_whr  = 1308832;
    const size_t NEED_FC = (size_t)(1308832 + 16384000) * 4;
    const size_t o_pl   = 17692832;
    const size_t o_gw   = o_pl + 6 * 8192;
    const size_t o_cnt  = o_gw + 16777216;
    const size_t NEED_ALL = (o_cnt + 128) * 4;

    float* xcur = ws + o_xcur;
    float* h0 = ws + o_st, *h1 = h0 + 32768, *c0 = h1 + 32768, *c1 = c0 + 32768;
    float* gpart = ws + o_gp;
    float* psum = ws + o_ps;
    float* pm1  = ws + o_m1;
    float* pm2  = ws + o_m2;
    int*   pi1  = (int*)(ws + o_i1);
    int*   pi2  = (int*)(ws + o_i2);
    float* lt   = ws + o_lt;
    unsigned short* hbr = (unsigned short*)(ws + o_hbr);
    unsigned short* Whr = (unsigned short*)(ws + o_whr);
    unsigned short* xHi   = (unsigned short*)(ws + o_pl);
    unsigned short* xMid  = xHi + 32768;
    unsigned short* h0Hi  = xMid + 32768;
    unsigned short* h0Mid = h0Hi + 32768;
    unsigned short* h1Hi  = h0Mid + 32768;
    unsigned short* h1Mid = h1Hi + 32768;
    unsigned short* Gw = (unsigned short*)(ws + o_gw);
    // concat gate planes: [layer][plane] of 8M bf16 each
    unsigned short* gw2[2][2];
    for (int L = 0; L < 2; L++)
        for (int p = 0; p < 2; p++)
            gw2[L][p] = Gw + ((size_t)L * 2 + p) * (2 * GWM);

    const size_t G4 = (size_t)G;
    const bool fc_ok  = (ws_size >= NEED_FC);
    const bool all_ok = (ws_size >= NEED_ALL);

    if (fc_ok)
        k_conv<<<4096, 256, 0, stream>>>(Wfc, Whr);

    if (all_ok) {
        k_conv_g2<<<4096, 256, 0, stream>>>(Wih, Whh, gw2[0][0], gw2[0][1]);
        k_conv_g2<<<4096, 256, 0, stream>>>(Wih + G4 * EMBD, Whh + G4 * HID,
                                            gw2[1][0], gw2[1][1]);
        k_init_m<<<B, 256, 0, stream>>>(x, emb, xcur, ws + o_st,
                                        xHi, xMid, h0Hi, h0Mid, h1Hi, h1Mid);
        for (int t = 0; t < TS; t++) {
            k_layer_f<<<256, 512, 0, stream>>>(
                gw2[0][0], gw2[0][1], xHi, xMid, h0Hi, h0Mid,
                bih, bhh, c0, h0Hi, h0Mid, nullptr);
            k_layer_f<<<256, 512, 0, stream>>>(
                gw2[1][0], gw2[1][1], h0Hi, h0Mid, h1Hi, h1Mid,
                bih + G, bhh + G, c1, h1Hi, h1Mid, h1);
            k_fc_mfma<<<NFM, 512, 0, stream>>>(Whr, h1Hi, bfc, x, t,
                                               psum, pm1, pm2, pi1, pi2, lt);
            k_fin2<<<B, 512, 0, stream>>>(psum, pm1, pm2, pi1, pi2, lt,
                                          h1, Wfc, bfc, emb, xcur,
                                          xHi, xMid, out, t);
        }
        return;
    }

    // ---- R14 tier: f32 gates + MFMA FC + separate fin ----
    k_init<<<B, 256, 0, stream>>>(x, emb, xcur, ws + o_st);
    for (int t = 0; t < TS; t++) {
        k_layer<<<dim3(32, KSL), 512, 0, stream>>>(xcur, h0, Wih, Whh, gpart);
        k_act<<<128, 256, 0, stream>>>(gpart, bih, bhh, c0, h0, hbr);
        k_layer<<<dim3(32, KSL), 512, 0, stream>>>(h0, h1, Wih + G4 * EMBD,
                                                   Whh + G4 * HID, gpart);
        k_act<<<128, 256, 0, stream>>>(gpart, bih + G, bhh + G, c1, h1, hbr);
        k_fc_mfma<<<NFM, 512, 0, stream>>>(Whr, hbr, bfc, x, t,
                                           psum, pm1, pm2, pi1, pi2, lt);
        k_fin2<<<B, 512, 0, stream>>>(psum, pm1, pm2, pi1, pi2, lt,
                                      h1, Wfc, bfc, emb, xcur,
                                      hbr, hbr, out, t);
    }
}

// Round 18
// 6823.912 us; speedup vs baseline: 5.7875x; 1.0628x over previous
//
#include <hip/hip_runtime.h>
#include <hip/hip_bf16.h>
#include <math.h>

#define B    32
#define EMBD 1024
#define HID  1024
#define G    4096
#define V    32000
#define TS   128
#define XROW (TS + 1)
#define KSL  8
#define NFM  500
#define GAPT 2e-3f
#define GWM  (4096 * 1024)

typedef short bf16x8 __attribute__((ext_vector_type(8)));
typedef float f32x4  __attribute__((ext_vector_type(4)));

#define FMA4(acc, W_, V_) \
  acc = fmaf((W_).x,(V_).x, fmaf((W_).y,(V_).y, fmaf((W_).z,(V_).z, fmaf((W_).w,(V_).w,(acc)))))

__device__ __forceinline__ unsigned short f2bu(float x) {
    __hip_bfloat16 b = __float2bfloat16(x);
    return *reinterpret_cast<unsigned short*>(&b);
}
__device__ __forceinline__ float b2f(unsigned short u) {
    union { unsigned int v; float f; } c; c.v = ((unsigned int)u) << 16; return c.f;
}
__device__ __forceinline__ void ins2(float m, int i, float& m1, int& i1,
                                     float& m2, int& i2) {
    if (m > m1 || (m == m1 && i < i1)) { m2 = m1; i2 = i1; m1 = m; i1 = i; }
    else if (m > m2 || (m == m2 && i < i2)) { m2 = m; i2 = i; }
}
__device__ __forceinline__ size_t pidx_act(int b, int jh) {
    const int kb = jh >> 5, kslot = (jh >> 3) & 3, e = jh & 7;
    const int lane = kslot * 16 + (b & 15);
    return ((((size_t)(b >> 4)) * 32 + kb) * 64 + lane) * 8 + e;
}

// ---------------- FC weight bf16 fragment-major reorder (R14-verified) -----
__global__ __launch_bounds__(256) void k_conv(
    const float* __restrict__ W, unsigned short* __restrict__ out)
{
    const int ngrp = V * HID / 8;
    for (int o = blockIdx.x * 256 + threadIdx.x; o < ngrp; o += gridDim.x * 256) {
        const int lane = o & 63, kb = (o >> 6) & 31, tile = o >> 11;
        const int row = tile * 16 + (lane & 15);
        const int k0  = kb * 32 + (lane >> 4) * 8;
        const float4 v0 = *(const float4*)(W + (size_t)row * 1024 + k0);
        const float4 v1 = *(const float4*)(W + (size_t)row * 1024 + k0 + 4);
        ushort4 a, b;
        a.x = f2bu(v0.x); a.y = f2bu(v0.y); a.z = f2bu(v0.z); a.w = f2bu(v0.w);
        b.x = f2bu(v1.x); b.y = f2bu(v1.y); b.z = f2bu(v1.z); b.w = f2bu(v1.w);
        ((ushort4*)out)[o * 2]     = a;
        ((ushort4*)out)[o * 2 + 1] = b;
    }
}

// ---------------- gate weights: concat-K, act-grouped tiles (R17-verified) --
__global__ __launch_bounds__(256) void k_conv_g2(
    const float* __restrict__ Wih, const float* __restrict__ Whh,
    unsigned short* __restrict__ hi, unsigned short* __restrict__ mid)
{
    const int ngrp = 256 * 64 * 64;
    for (int o = blockIdx.x * 256 + threadIdx.x; o < ngrp; o += gridDim.x * 256) {
        const int lane = o & 63, kbg = (o >> 6) & 63, tile = o >> 12;
        const int ir = lane & 15;
        const int gate = ir >> 2, jr = ir & 3;
        const int row = gate * 1024 + tile * 4 + jr;
        const bool xp = (kbg < 32);
        const float* src = xp ? Wih : Whh;
        const int kbl = xp ? kbg : (kbg - 32);
        const int k0 = kbl * 32 + (lane >> 4) * 8;
#pragma unroll
        for (int q = 0; q < 2; q++) {
            const float4 v = *(const float4*)(src + (size_t)row * 1024 + k0 + q * 4);
            ushort4 h, m;
            h.x = f2bu(v.x); m.x = f2bu(v.x - b2f(h.x));
            h.y = f2bu(v.y); m.y = f2bu(v.y - b2f(h.y));
            h.z = f2bu(v.z); m.z = f2bu(v.z - b2f(h.z));
            h.w = f2bu(v.w); m.w = f2bu(v.w - b2f(h.w));
            ((ushort4*)hi)[o * 2 + q]  = h;
            ((ushort4*)mid)[o * 2 + q] = m;
        }
    }
}

// ---------------- init (mfma tier): states=0, planes ----------------
__global__ __launch_bounds__(256) void k_init_m(
    const int* __restrict__ x, const float* __restrict__ emb,
    float* __restrict__ xcur, float* __restrict__ st,
    unsigned short* __restrict__ xHi, unsigned short* __restrict__ xMid,
    unsigned short* __restrict__ h0Hi, unsigned short* __restrict__ h0Mid,
    unsigned short* __restrict__ h1Hi, unsigned short* __restrict__ h1Mid)
{
    const int b = blockIdx.x, tid = threadIdx.x;
    float4 z = {0.f, 0.f, 0.f, 0.f};
#pragma unroll
    for (int q = 0; q < 4; q++)
        ((float4*)(st + (size_t)q * B * HID + (size_t)b * HID))[tid] = z;
    const int tok = x[b * XROW];
    const float4 ev = ((const float4*)(emb + (size_t)tok * EMBD))[tid];
    ((float4*)(xcur + (size_t)b * EMBD))[tid] = ev;
    const int jh0 = tid * 4;
    const size_t p0 = pidx_act(b, jh0);
    const float e4[4] = {ev.x, ev.y, ev.z, ev.w};
#pragma unroll
    for (int q = 0; q < 4; q++) {
        const unsigned short h = f2bu(e4[q]);
        xHi[p0 + q]  = h;
        xMid[p0 + q] = f2bu(e4[q] - b2f(h));
        h0Hi[p0 + q] = 0; h0Mid[p0 + q] = 0;
        h1Hi[p0 + q] = 0; h1Mid[p0 + q] = 0;
    }
}

// ---------------- fused gates GEMM + in-block act (16-wave k-split) ---------
// grid 256 (jq = 4 jh each), block 1024 = 16 waves; wave = 4 kbg of concat-64.
// Waves 0-7: x-part; 8-15: h-part. LDS 16-way reduce, then in-block act.
__global__ __launch_bounds__(1024) void k_layer_f(
    const unsigned short* __restrict__ Ahi, const unsigned short* __restrict__ Amid,
    const unsigned short* __restrict__ xHi, const unsigned short* __restrict__ xMid,
    const unsigned short* __restrict__ hHi, const unsigned short* __restrict__ hMid,
    const float* __restrict__ bih, const float* __restrict__ bhh,
    float* __restrict__ c2,
    unsigned short* __restrict__ oHi, unsigned short* __restrict__ oMid,
    float* __restrict__ h_f32)
{
    __shared__ float red[16 * 16 * 33];     // 33.8 KB
    const int tid = threadIdx.x;
    const int wv  = tid >> 6;               // 0..15 (k-chunk)
    const int lane = tid & 63;
    const int jq  = blockIdx.x;             // 0..255
    const bool xp = (wv < 8);
    const unsigned short* Bh = xp ? xHi : hHi;
    const unsigned short* Bm = xp ? xMid : hMid;
    const int kbl0 = xp ? (wv * 4) : ((wv - 8) * 4);

    f32x4 acc0 = {0.f, 0.f, 0.f, 0.f};
    f32x4 acc1 = {0.f, 0.f, 0.f, 0.f};

#pragma unroll
    for (int i = 0; i < 4; i++) {
        const int kbg = wv * 4 + i;
        const int kbl = kbl0 + i;
        const size_t aoff = (((size_t)jq * 64 + kbg) * 64 + lane) * 8;
        const bf16x8 Avh = *(const bf16x8*)(Ahi + aoff);
        const bf16x8 Avm = *(const bf16x8*)(Amid + aoff);
        const size_t b0off = (((size_t)kbl) * 64 + lane) * 8;
        const size_t b1off = (((size_t)(32 + kbl)) * 64 + lane) * 8;
        const bf16x8 B0h = *(const bf16x8*)(Bh + b0off);
        const bf16x8 B0m = *(const bf16x8*)(Bm + b0off);
        const bf16x8 B1h = *(const bf16x8*)(Bh + b1off);
        const bf16x8 B1m = *(const bf16x8*)(Bm + b1off);
        acc0 = __builtin_amdgcn_mfma_f32_16x16x32_bf16(Avh, B0h, acc0, 0, 0, 0);
        acc1 = __builtin_amdgcn_mfma_f32_16x16x32_bf16(Avh, B1h, acc1, 0, 0, 0);
        acc0 = __builtin_amdgcn_mfma_f32_16x16x32_bf16(Avh, B0m, acc0, 0, 0, 0);
        acc1 = __builtin_amdgcn_mfma_f32_16x16x32_bf16(Avh, B1m, acc1, 0, 0, 0);
        acc0 = __builtin_amdgcn_mfma_f32_16x16x32_bf16(Avm, B0h, acc0, 0, 0, 0);
        acc1 = __builtin_amdgcn_mfma_f32_16x16x32_bf16(Avm, B1h, acc1, 0, 0, 0);
    }

    // D: in-tile row=(lane>>4)*4+r, col=lane&15 (batch within half)
    {
        const int bcol = lane & 15;
#pragma unroll
        for (int r = 0; r < 4; r++) {
            const int rd = (lane >> 4) * 4 + r;
            red[(wv * 16 + rd) * 33 + bcol]      = acc0[r];
            red[(wv * 16 + rd) * 33 + 16 + bcol] = acc1[r];
        }
    }
    __syncthreads();

    if (tid < 128) {
        const int jr = tid >> 5, b = tid & 31;
        const int jh = jq * 4 + jr;
        float gs[4];
#pragma unroll
        for (int g = 0; g < 4; g++) {
            const int rd = g * 4 + jr;
            float v = 0.f;
#pragma unroll
            for (int w = 0; w < 16; w++)
                v += red[(w * 16 + rd) * 33 + b];
            gs[g] = v + bih[g * 1024 + jh] + bhh[g * 1024 + jh];
        }
        const float i = 1.f / (1.f + expf(-gs[0]));
        const float f = 1.f / (1.f + expf(-gs[1]));
        const float g = tanhf(gs[2]);
        const float o = 1.f / (1.f + expf(-gs[3]));
        const int ci = jh * 32 + b;
        const float cn = f * c2[ci] + i * g;
        c2[ci] = cn;
        const float hv = o * tanhf(cn);
        if (h_f32) h_f32[(size_t)b * HID + jh] = hv;
        const size_t p = pidx_act(b, jh);
        const unsigned short uh = f2bu(hv);
        oHi[p]  = uh;
        oMid[p] = f2bu(hv - b2f(uh));
    }
}

// ---------------- MFMA FC (R14/R15-verified) --------------------------------
__global__ __launch_bounds__(512, 4) void k_fc_mfma(
    const unsigned short* __restrict__ Whr, const unsigned short* __restrict__ hbr,
    const float* __restrict__ bfc, const int* __restrict__ x, int t,
    float* __restrict__ psum, float* __restrict__ pm1, float* __restrict__ pm2,
    int* __restrict__ pi1, int* __restrict__ pi2, float* __restrict__ lt)
{
    __shared__ float logits[64 * 33];
    __shared__ float segS[16 * 32], segM1[16 * 32], segM2[16 * 32];
    __shared__ int   segI1[16 * 32], segI2[16 * 32];

    const int tid = threadIdx.x;
    const int wv  = tid >> 6;
    const int kh  = wv >> 2;
    const int rg  = wv & 3;
    const int lane = tid & 63;
    const int jb  = blockIdx.x;
    const int j0  = jb * 64;

    const unsigned short* Ab = Whr + ((size_t)(jb * 4 + rg) * 32 * 64) * 8;

    f32x4 acc0 = {0.f, 0.f, 0.f, 0.f};
    f32x4 acc1 = {0.f, 0.f, 0.f, 0.f};

#pragma unroll 4
    for (int i = 0; i < 16; i++) {
        const int kb = kh * 16 + i;
        const bf16x8 Av = *(const bf16x8*)(Ab + ((size_t)kb * 64 + lane) * 8);
        const bf16x8 B0 = *(const bf16x8*)(hbr + (((size_t)kb) * 64 + lane) * 8);
        const bf16x8 B1 = *(const bf16x8*)(hbr + (((size_t)(32 + kb)) * 64 + lane) * 8);
        acc0 = __builtin_amdgcn_mfma_f32_16x16x32_bf16(Av, B0, acc0, 0, 0, 0);
        acc1 = __builtin_amdgcn_mfma_f32_16x16x32_bf16(Av, B1, acc1, 0, 0, 0);
    }

    const int rbase = rg * 16 + (lane >> 4) * 4;
    const int bcol  = lane & 15;
    if (kh == 0) {
#pragma unroll
        for (int r = 0; r < 4; r++) {
            const int rw = rbase + r;
            logits[rw * 33 + bcol]      = acc0[r] + bfc[j0 + rw];
            logits[rw * 33 + 16 + bcol] = acc1[r];
        }
    }
    __syncthreads();
    if (kh == 1) {
#pragma unroll
        for (int r = 0; r < 4; r++) {
            const int rw = rbase + r;
            logits[rw * 33 + bcol]      += acc0[r];
            logits[rw * 33 + 16 + bcol] += acc1[r] + bfc[j0 + rw];
        }
    }
    __syncthreads();

    {
        const int b = tid & 31, seg = tid >> 5;
        float ls = 0.f, m1 = -1e30f, m2 = -1e30f;
        int i1 = 0x7fffffff, i2 = 0x7fffffff;
#pragma unroll
        for (int i = 0; i < 4; i++) {
            const int rw = seg * 4 + i;
            const float l = logits[rw * 33 + b];
            ls += expf(l);
            ins2(l, j0 + rw, m1, i1, m2, i2);
        }
        segS[seg * 32 + b] = ls;
        segM1[seg * 32 + b] = m1; segI1[seg * 32 + b] = i1;
        segM2[seg * 32 + b] = m2; segI2[seg * 32 + b] = i2;
    }
    __syncthreads();
    if (tid < 32) {
        const int b = tid;
        float ts = 0.f, m1 = -1e30f, m2 = -1e30f;
        int i1 = 0x7fffffff, i2 = 0x7fffffff;
#pragma unroll
        for (int seg = 0; seg < 16; seg++) {
            ts += segS[seg * 32 + b];
            ins2(segM1[seg * 32 + b], segI1[seg * 32 + b], m1, i1, m2, i2);
            ins2(segM2[seg * 32 + b], segI2[seg * 32 + b], m1, i1, m2, i2);
        }
        psum[b * NFM + jb] = ts;
        pm1[b * NFM + jb] = m1; pi1[b * NFM + jb] = i1;
        pm2[b * NFM + jb] = m2; pi2[b * NFM + jb] = i2;
        const int tgt = x[b * XROW + t + 1];
        const int loc = tgt - j0;
        if (loc >= 0 && loc < 64) lt[b] = logits[loc * 33 + b];
    }
}

// ---------------- finalize + guard + next embedding (+x planes) ------------
__global__ __launch_bounds__(512) void k_fin2(
    const float* __restrict__ psum, const float* __restrict__ pm1,
    const float* __restrict__ pm2, const int* __restrict__ pi1,
    const int* __restrict__ pi2, const float* __restrict__ lt,
    const float* __restrict__ h1, const float* __restrict__ Wfc,
    const float* __restrict__ bfc, const float* __restrict__ emb,
    float* __restrict__ xcur, unsigned short* __restrict__ xHi,
    unsigned short* __restrict__ xMid, float* __restrict__ out, int t)
{
    __shared__ float ss[512], sm1[512], sm2[512];
    __shared__ int si1[512], si2[512];
    __shared__ int sW, sA, sB2, sNeed;
    const int b = blockIdx.x, tid = threadIdx.x;

    const bool v = (tid < NFM);
    ss[tid]  = v ? psum[b * NFM + tid] : 0.f;
    sm1[tid] = v ? pm1[b * NFM + tid] : -1e30f;
    sm2[tid] = v ? pm2[b * NFM + tid] : -1e30f;
    si1[tid] = v ? pi1[b * NFM + tid] : 0x7fffffff;
    si2[tid] = v ? pi2[b * NFM + tid] : 0x7fffffff;
    __syncthreads();
    for (int s = 256; s > 0; s >>= 1) {
        if (tid < s) {
            ss[tid] += ss[tid + s];
            float a1 = sm1[tid], a2 = sm2[tid];
            int x1 = si1[tid], x2 = si2[tid];
            ins2(sm1[tid + s], si1[tid + s], a1, x1, a2, x2);
            ins2(sm2[tid + s], si2[tid + s], a1, x1, a2, x2);
            sm1[tid] = a1; si1[tid] = x1; sm2[tid] = a2; si2[tid] = x2;
        }
        __syncthreads();
    }
    if (tid == 0) {
        out[(size_t)b * TS + t] = expf(lt[b]) / ss[0];
        sW = si1[0]; sA = si1[0]; sB2 = si2[0];
        sNeed = (sm1[0] - sm2[0] < GAPT) ? 1 : 0;
    }
    __syncthreads();

    if (sNeed) {
        const int ia = sA, ib = sB2;
        float a1 = 0.f, a2 = 0.f;
        if (tid < 256) {
            const float4 hv = ((const float4*)(h1 + (size_t)b * HID))[tid];
            const float4 w1 = ((const float4*)(Wfc + (size_t)ia * HID))[tid];
            const float4 w2 = ((const float4*)(Wfc + (size_t)ib * HID))[tid];
            a1 = hv.x * w1.x + hv.y * w1.y + hv.z * w1.z + hv.w * w1.w;
            a2 = hv.x * w2.x + hv.y * w2.y + hv.z * w2.z + hv.w * w2.w;
        }
        __syncthreads();
        sm1[tid] = a1; sm2[tid] = a2;
        __syncthreads();
        for (int s = 128; s > 0; s >>= 1) {
            if (tid < s) { sm1[tid] += sm1[tid + s]; sm2[tid] += sm2[tid + s]; }
            __syncthreads();
        }
        if (tid == 0) {
            const float l1 = sm1[0] + bfc[ia];
            const float l2 = sm2[0] + bfc[ib];
            if (l2 > l1 || (l2 == l1 && ib < ia)) sW = ib;
        }
        __syncthreads();
    }
    if (tid < 256) {
        const float4 ev = ((const float4*)(emb + (size_t)sW * EMBD))[tid];
        ((float4*)(xcur + (size_t)b * EMBD))[tid] = ev;
        const int jh0 = tid * 4;
        const size_t p0 = pidx_act(b, jh0);
        const float e4[4] = {ev.x, ev.y, ev.z, ev.w};
#pragma unroll
        for (int q = 0; q < 4; q++) {
            const unsigned short h = f2bu(e4[q]);
            xHi[p0 + q]  = h;
            xMid[p0 + q] = f2bu(e4[q] - b2f(h));
        }
    }
}

// ================= R14-tier fallback kernels (f32 gates) =================

__global__ __launch_bounds__(256) void k_init(
    const int* __restrict__ x, const float* __restrict__ emb,
    float* __restrict__ xcur, float* __restrict__ st)
{
    const int b = blockIdx.x, tid = threadIdx.x;
    float4 z = {0.f, 0.f, 0.f, 0.f};
#pragma unroll
    for (int q = 0; q < 4; q++)
        ((float4*)(st + (size_t)q * B * HID + (size_t)b * HID))[tid] = z;
    const int tok = x[b * XROW];
    ((float4*)(xcur + (size_t)b * EMBD))[tid] =
        ((const float4*)(emb + (size_t)tok * EMBD))[tid];
}

__global__ __launch_bounds__(512) void k_layer(
    const float* __restrict__ xin, const float* __restrict__ hin,
    const float* __restrict__ Wih, const float* __restrict__ Whh,
    float* __restrict__ gpart)
{
    __shared__ float4 sb4x[2048];
    const int tid = threadIdx.x;
    const int ww  = tid >> 6;
    const int lane = tid & 63;
    const int rs  = lane >> 2;
    const int kq  = lane & 3;
    const int jb  = blockIdx.x;
    const int ks  = blockIdx.y;
    const bool xpart = (ks < 4);
    const float* __restrict__ src = xpart ? xin : hin;
    const float* __restrict__ Wb  = xpart ? Wih : Whh;
    const int cchunk = (ks & 3) * 64;

#pragma unroll
    for (int e = 0; e < 4; e++) {
        const int fi = tid + e * 512;
        const int b = fi >> 6, off = fi & 63;
        sb4x[fi] = ((const float4*)(src + (size_t)b * 1024))[cchunk + off];
    }
    __syncthreads();

    const int j0 = jb * 128;
    const float4* W4 = (const float4*)Wb;
    const float4* wp[8];
#pragma unroll
    for (int jj = 0; jj < 8; jj++)
        wp[jj] = W4 + (size_t)(j0 + rs * 8 + jj) * 256 + cchunk;

    float acc[8][4];
#pragma unroll
    for (int jj = 0; jj < 8; jj++)
#pragma unroll
        for (int bl = 0; bl < 4; bl++) acc[jj][bl] = 0.f;

#pragma unroll 4
    for (int s = 0; s < 16; s++) {
        const int col = s * 4 + kq;
        float4 w[8];
#pragma unroll
        for (int jj = 0; jj < 8; jj++) w[jj] = wp[jj][col];
#pragma unroll
        for (int bl = 0; bl < 4; bl++) {
            const float4 xv = sb4x[(ww * 4 + bl) * 64 + col];
#pragma unroll
            for (int jj = 0; jj < 8; jj++) FMA4(acc[jj][bl], w[jj], xv);
        }
    }

#pragma unroll
    for (int jj = 0; jj < 8; jj++)
#pragma unroll
        for (int bl = 0; bl < 4; bl++) {
            acc[jj][bl] += __shfl_xor(acc[jj][bl], 1);
            acc[jj][bl] += __shfl_xor(acc[jj][bl], 2);
        }

#pragma unroll
    for (int q = 0; q < 2; q++) {
        const int jjw = 2 * kq + q;
        const int r = j0 + rs * 8 + jjw;
#pragma unroll
        for (int bl = 0; bl < 4; bl++) {
            const int b = ww * 4 + bl;
            float v = acc[0][bl];
#pragma unroll
            for (int jj = 1; jj < 8; jj++)
                if (jjw == jj) v = acc[jj][bl];
            gpart[((size_t)ks * B + b) * G + r] = v;
        }
    }
}

__global__ __launch_bounds__(256) void k_act(
    const float* __restrict__ part, const float* __restrict__ bih,
    const float* __restrict__ bhh, float* __restrict__ c, float* __restrict__ h,
    unsigned short* __restrict__ hbr)
{
    const int idx = blockIdx.x * 256 + threadIdx.x;
    const int b = idx >> 10, jh = idx & 1023;
    float gi = bih[jh]        + bhh[jh];
    float gf = bih[jh + 1024] + bhh[jh + 1024];
    float gg = bih[jh + 2048] + bhh[jh + 2048];
    float go = bih[jh + 3072] + bhh[jh + 3072];
#pragma unroll
    for (int ks = 0; ks < KSL; ks++) {
        const float* p = part + ((size_t)ks * B + b) * G;
        gi += p[jh]; gf += p[jh + 1024]; gg += p[jh + 2048]; go += p[jh + 3072];
    }
    const float i = 1.f / (1.f + expf(-gi));
    const float f = 1.f / (1.f + expf(-gf));
    const float g = tanhf(gg);
    const float o = 1.f / (1.f + expf(-go));
    const float cn = f * c[idx] + i * g;
    c[idx] = cn;
    const float hv = o * tanhf(cn);
    h[idx] = hv;
    hbr[pidx_act(b, jh)] = f2bu(hv);
}

// ================= launch =================

extern "C" void kernel_launch(void* const* d_in, const int* in_sizes, int n_in,
                              void* d_out, int out_size, void* d_ws, size_t ws_size,
                              hipStream_t stream)
{
    const int*   x   = (const int*)  d_in[0];
    const float* emb = (const float*)d_in[1];
    const float* Wih = (const float*)d_in[2];
    const float* Whh = (const float*)d_in[3];
    const float* bih = (const float*)d_in[4];
    const float* bhh = (const float*)d_in[5];
    const float* Wfc = (const float*)d_in[6];
    const float* bfc = (const float*)d_in[7];
    float* out = (float*)d_out;
    float* ws = (float*)d_ws;

    // layout (float slots) — R15-compatible
    const size_t o_xcur = 0;
    const size_t o_st   = 32768;
    const size_t o_gp   = 163840;
    const size_t o_ps   = 1212416;
    const size_t o_m1   = 1228416;
    const size_t o_m2   = 1244416;
    const size_t o_i1   = 1260416;
    const size_t o_i2   = 1276416;
    const size_t o_lt   = 1292416;
    const size_t o_hbr  = 1292448;
    const size_t o_whr  = 1308832;
    const size_t NEED_FC = (size_t)(1308832 + 16384000) * 4;
    const size_t o_pl   = 17692832;
    const size_t o_gw   = o_pl + 6 * 8192;
    const size_t o_cnt  = o_gw + 16777216;
    const size_t NEED_ALL = (o_cnt + 128) * 4;

    float* xcur = ws + o_xcur;
    float* h0 = ws + o_st, *h1 = h0 + 32768, *c0 = h1 + 32768, *c1 = c0 + 32768;
    float* gpart = ws + o_gp;
    float* psum = ws + o_ps;
    float* pm1  = ws + o_m1;
    float* pm2  = ws + o_m2;
    int*   pi1  = (int*)(ws + o_i1);
    int*   pi2  = (int*)(ws + o_i2);
    float* lt   = ws + o_lt;
    unsigned short* hbr = (unsigned short*)(ws + o_hbr);
    unsigned short* Whr = (unsigned short*)(ws + o_whr);
    unsigned short* xHi   = (unsigned short*)(ws + o_pl);
    unsigned short* xMid  = xHi + 32768;
    unsigned short* h0Hi  = xMid + 32768;
    unsigned short* h0Mid = h0Hi + 32768;
    unsigned short* h1Hi  = h0Mid + 32768;
    unsigned short* h1Mid = h1Hi + 32768;
    unsigned short* Gw = (unsigned short*)(ws + o_gw);
    unsigned short* gw2[2][2];
    for (int L = 0; L < 2; L++)
        for (int p = 0; p < 2; p++)
            gw2[L][p] = Gw + ((size_t)L * 2 + p) * (2 * GWM);

    const size_t G4 = (size_t)G;
    const bool fc_ok  = (ws_size >= NEED_FC);
    const bool all_ok = (ws_size >= NEED_ALL);

    if (fc_ok)
        k_conv<<<4096, 256, 0, stream>>>(Wfc, Whr);

    if (all_ok) {
        k_conv_g2<<<4096, 256, 0, stream>>>(Wih, Whh, gw2[0][0], gw2[0][1]);
        k_conv_g2<<<4096, 256, 0, stream>>>(Wih + G4 * EMBD, Whh + G4 * HID,
                                            gw2[1][0], gw2[1][1]);
        k_init_m<<<B, 256, 0, stream>>>(x, emb, xcur, ws + o_st,
                                        xHi, xMid, h0Hi, h0Mid, h1Hi, h1Mid);
        for (int t = 0; t < TS; t++) {
            k_layer_f<<<256, 1024, 0, stream>>>(
                gw2[0][0], gw2[0][1], xHi, xMid, h0Hi, h0Mid,
                bih, bhh, c0, h0Hi, h0Mid, nullptr);
            k_layer_f<<<256, 1024, 0, stream>>>(
                gw2[1][0], gw2[1][1], h0Hi, h0Mid, h1Hi, h1Mid,
                bih + G, bhh + G, c1, h1Hi, h1Mid, h1);
            k_fc_mfma<<<NFM, 512, 0, stream>>>(Whr, h1Hi, bfc, x, t,
                                               psum, pm1, pm2, pi1, pi2, lt);
            k_fin2<<<B, 512, 0, stream>>>(psum, pm1, pm2, pi1, pi2, lt,
                                          h1, Wfc, bfc, emb, xcur,
                                          xHi, xMid, out, t);
        }
        return;
    }

    // ---- R14 tier: f32 gates + MFMA FC + separate fin ----
    k_init<<<B, 256, 0, stream>>>(x, emb, xcur, ws + o_st);
    for (int t = 0; t < TS; t++) {
        k_layer<<<dim3(32, KSL), 512, 0, stream>>>(xcur, h0, Wih, Whh, gpart);
        k_act<<<128, 256, 0, stream>>>(gpart, bih, bhh, c0, h0, hbr);
        k_layer<<<dim3(32, KSL), 512, 0, stream>>>(h0, h1, Wih + G4 * EMBD,
                                                   Whh + G4 * HID, gpart);
        k_act<<<128, 256, 0, stream>>>(gpart, bih + G, bhh + G, c1, h1, hbr);
        k_fc_mfma<<<NFM, 512, 0, stream>>>(Whr, hbr, bfc, x, t,
                                           psum, pm1, pm2, pi1, pi2, lt);
        k_fin2<<<B, 512, 0, stream>>>(psum, pm1, pm2, pi1, pi2, lt,
                                      h1, Wfc, bfc, emb, xcur,
                                      hbr, hbr, out, t);
    }
}

// Round 19
// 6642.414 us; speedup vs baseline: 5.9456x; 1.0273x over previous
//
#include <hip/hip_runtime.h>
#include <hip/hip_bf16.h>
#include <math.h>

#define B    32
#define EMBD 1024
#define HID  1024
#define G    4096
#define V    32000
#define TS   128
#define XROW (TS + 1)
#define KSL  8
#define NFM  500
#define GAPT 2e-3f
#define GWM  (4096 * 1024)

typedef short bf16x8 __attribute__((ext_vector_type(8)));
typedef float f32x4  __attribute__((ext_vector_type(4)));

#define FMA4(acc, W_, V_) \
  acc = fmaf((W_).x,(V_).x, fmaf((W_).y,(V_).y, fmaf((W_).z,(V_).z, fmaf((W_).w,(V_).w,(acc)))))

__device__ __forceinline__ unsigned short f2bu(float x) {
    __hip_bfloat16 b = __float2bfloat16(x);
    return *reinterpret_cast<unsigned short*>(&b);
}
__device__ __forceinline__ float b2f(unsigned short u) {
    union { unsigned int v; float f; } c; c.v = ((unsigned int)u) << 16; return c.f;
}
__device__ __forceinline__ void ins2(float m, int i, float& m1, int& i1,
                                     float& m2, int& i2) {
    if (m > m1 || (m == m1 && i < i1)) { m2 = m1; i2 = i1; m1 = m; i1 = i; }
    else if (m > m2 || (m == m2 && i < i2)) { m2 = m; i2 = i; }
}
__device__ __forceinline__ size_t pidx_act(int b, int jh) {
    const int kb = jh >> 5, kslot = (jh >> 3) & 3, e = jh & 7;
    const int lane = kslot * 16 + (b & 15);
    return ((((size_t)(b >> 4)) * 32 + kb) * 64 + lane) * 8 + e;
}

// ---------------- FC weight bf16 fragment-major reorder (R14-verified) -----
__global__ __launch_bounds__(256) void k_conv(
    const float* __restrict__ W, unsigned short* __restrict__ out)
{
    const int ngrp = V * HID / 8;
    for (int o = blockIdx.x * 256 + threadIdx.x; o < ngrp; o += gridDim.x * 256) {
        const int lane = o & 63, kb = (o >> 6) & 31, tile = o >> 11;
        const int row = tile * 16 + (lane & 15);
        const int k0  = kb * 32 + (lane >> 4) * 8;
        const float4 v0 = *(const float4*)(W + (size_t)row * 1024 + k0);
        const float4 v1 = *(const float4*)(W + (size_t)row * 1024 + k0 + 4);
        ushort4 a, b;
        a.x = f2bu(v0.x); a.y = f2bu(v0.y); a.z = f2bu(v0.z); a.w = f2bu(v0.w);
        b.x = f2bu(v1.x); b.y = f2bu(v1.y); b.z = f2bu(v1.z); b.w = f2bu(v1.w);
        ((ushort4*)out)[o * 2]     = a;
        ((ushort4*)out)[o * 2 + 1] = b;
    }
}

// ---------------- gate weights: concat-K, act-grouped tiles (R17-verified) --
__global__ __launch_bounds__(256) void k_conv_g2(
    const float* __restrict__ Wih, const float* __restrict__ Whh,
    unsigned short* __restrict__ hi, unsigned short* __restrict__ mid)
{
    const int ngrp = 256 * 64 * 64;
    for (int o = blockIdx.x * 256 + threadIdx.x; o < ngrp; o += gridDim.x * 256) {
        const int lane = o & 63, kbg = (o >> 6) & 63, tile = o >> 12;
        const int ir = lane & 15;
        const int gate = ir >> 2, jr = ir & 3;
        const int row = gate * 1024 + tile * 4 + jr;
        const bool xp = (kbg < 32);
        const float* src = xp ? Wih : Whh;
        const int kbl = xp ? kbg : (kbg - 32);
        const int k0 = kbl * 32 + (lane >> 4) * 8;
#pragma unroll
        for (int q = 0; q < 2; q++) {
            const float4 v = *(const float4*)(src + (size_t)row * 1024 + k0 + q * 4);
            ushort4 h, m;
            h.x = f2bu(v.x); m.x = f2bu(v.x - b2f(h.x));
            h.y = f2bu(v.y); m.y = f2bu(v.y - b2f(h.y));
            h.z = f2bu(v.z); m.z = f2bu(v.z - b2f(h.z));
            h.w = f2bu(v.w); m.w = f2bu(v.w - b2f(h.w));
            ((ushort4*)hi)[o * 2 + q]  = h;
            ((ushort4*)mid)[o * 2 + q] = m;
        }
    }
}

// ---------------- init (mfma tier): states=0, planes ----------------
__global__ __launch_bounds__(256) void k_init_m(
    const int* __restrict__ x, const float* __restrict__ emb,
    float* __restrict__ xcur, float* __restrict__ st,
    unsigned short* __restrict__ xHi, unsigned short* __restrict__ xMid,
    unsigned short* __restrict__ h0Hi, unsigned short* __restrict__ h0Mid,
    unsigned short* __restrict__ h1Hi, unsigned short* __restrict__ h1Mid)
{
    const int b = blockIdx.x, tid = threadIdx.x;
    float4 z = {0.f, 0.f, 0.f, 0.f};
#pragma unroll
    for (int q = 0; q < 4; q++)
        ((float4*)(st + (size_t)q * B * HID + (size_t)b * HID))[tid] = z;
    const int tok = x[b * XROW];
    const float4 ev = ((const float4*)(emb + (size_t)tok * EMBD))[tid];
    ((float4*)(xcur + (size_t)b * EMBD))[tid] = ev;
    const int jh0 = tid * 4;
    const size_t p0 = pidx_act(b, jh0);
    const float e4[4] = {ev.x, ev.y, ev.z, ev.w};
#pragma unroll
    for (int q = 0; q < 4; q++) {
        const unsigned short h = f2bu(e4[q]);
        xHi[p0 + q]  = h;
        xMid[p0 + q] = f2bu(e4[q] - b2f(h));
        h0Hi[p0 + q] = 0; h0Mid[p0 + q] = 0;
        h1Hi[p0 + q] = 0; h1Mid[p0 + q] = 0;
    }
}

// ---------------- fused gates GEMM + in-block act (16-wave, R18-verified) ---
__global__ __launch_bounds__(1024) void k_layer_f(
    const unsigned short* __restrict__ Ahi, const unsigned short* __restrict__ Amid,
    const unsigned short* __restrict__ xHi, const unsigned short* __restrict__ xMid,
    const unsigned short* __restrict__ hHi, const unsigned short* __restrict__ hMid,
    const float* __restrict__ bih, const float* __restrict__ bhh,
    float* __restrict__ c2,
    unsigned short* __restrict__ oHi, unsigned short* __restrict__ oMid,
    float* __restrict__ h_f32)
{
    __shared__ float red[16 * 16 * 33];     // 33.8 KB
    const int tid = threadIdx.x;
    const int wv  = tid >> 6;               // 0..15 (k-chunk)
    const int lane = tid & 63;
    const int jq  = blockIdx.x;             // 0..255
    const bool xp = (wv < 8);
    const unsigned short* Bh = xp ? xHi : hHi;
    const unsigned short* Bm = xp ? xMid : hMid;
    const int kbl0 = xp ? (wv * 4) : ((wv - 8) * 4);

    f32x4 acc0 = {0.f, 0.f, 0.f, 0.f};
    f32x4 acc1 = {0.f, 0.f, 0.f, 0.f};

#pragma unroll
    for (int i = 0; i < 4; i++) {
        const int kbg = wv * 4 + i;
        const int kbl = kbl0 + i;
        const size_t aoff = (((size_t)jq * 64 + kbg) * 64 + lane) * 8;
        const bf16x8 Avh = *(const bf16x8*)(Ahi + aoff);
        const bf16x8 Avm = *(const bf16x8*)(Amid + aoff);
        const size_t b0off = (((size_t)kbl) * 64 + lane) * 8;
        const size_t b1off = (((size_t)(32 + kbl)) * 64 + lane) * 8;
        const bf16x8 B0h = *(const bf16x8*)(Bh + b0off);
        const bf16x8 B0m = *(const bf16x8*)(Bm + b0off);
        const bf16x8 B1h = *(const bf16x8*)(Bh + b1off);
        const bf16x8 B1m = *(const bf16x8*)(Bm + b1off);
        acc0 = __builtin_amdgcn_mfma_f32_16x16x32_bf16(Avh, B0h, acc0, 0, 0, 0);
        acc1 = __builtin_amdgcn_mfma_f32_16x16x32_bf16(Avh, B1h, acc1, 0, 0, 0);
        acc0 = __builtin_amdgcn_mfma_f32_16x16x32_bf16(Avh, B0m, acc0, 0, 0, 0);
        acc1 = __builtin_amdgcn_mfma_f32_16x16x32_bf16(Avh, B1m, acc1, 0, 0, 0);
        acc0 = __builtin_amdgcn_mfma_f32_16x16x32_bf16(Avm, B0h, acc0, 0, 0, 0);
        acc1 = __builtin_amdgcn_mfma_f32_16x16x32_bf16(Avm, B1h, acc1, 0, 0, 0);
    }

    {
        const int bcol = lane & 15;
#pragma unroll
        for (int r = 0; r < 4; r++) {
            const int rd = (lane >> 4) * 4 + r;
            red[(wv * 16 + rd) * 33 + bcol]      = acc0[r];
            red[(wv * 16 + rd) * 33 + 16 + bcol] = acc1[r];
        }
    }
    __syncthreads();

    if (tid < 128) {
        const int jr = tid >> 5, b = tid & 31;
        const int jh = jq * 4 + jr;
        float gs[4];
#pragma unroll
        for (int g = 0; g < 4; g++) {
            const int rd = g * 4 + jr;
            float v = 0.f;
#pragma unroll
            for (int w = 0; w < 16; w++)
                v += red[(w * 16 + rd) * 33 + b];
            gs[g] = v + bih[g * 1024 + jh] + bhh[g * 1024 + jh];
        }
        const float i = 1.f / (1.f + expf(-gs[0]));
        const float f = 1.f / (1.f + expf(-gs[1]));
        const float g = tanhf(gs[2]);
        const float o = 1.f / (1.f + expf(-gs[3]));
        const int ci = jh * 32 + b;
        const float cn = f * c2[ci] + i * g;
        c2[ci] = cn;
        const float hv = o * tanhf(cn);
        if (h_f32) h_f32[(size_t)b * HID + jh] = hv;
        const size_t p = pidx_act(b, jh);
        const unsigned short uh = f2bu(hv);
        oHi[p]  = uh;
        oMid[p] = f2bu(hv - b2f(uh));
    }
}

// ---------------- MFMA FC v4: B staged in LDS (aliased with logits) ---------
// grid 500, block 512 = 8 waves (2 kh x 4 rg). Block: 64 rows x 32 b.
__global__ __launch_bounds__(512, 4) void k_fc_mfma(
    const unsigned short* __restrict__ Whr, const unsigned short* __restrict__ hbr,
    const float* __restrict__ bfc, const int* __restrict__ x, int t,
    float* __restrict__ psum, float* __restrict__ pm1, float* __restrict__ pm2,
    int* __restrict__ pi1, int* __restrict__ pi2, float* __restrict__ lt)
{
    __shared__ char smem[65536];            // union: Bs (64 KB) / logits+segs
    unsigned short* Bs = (unsigned short*)smem;          // 32768 bf16
    float* logits = (float*)smem;                         // [64][33] = 8448 B
    float* segS   = (float*)(smem + 8448);                // 16*32*4 = 2048 B
    float* segM1  = (float*)(smem + 10496);
    float* segM2  = (float*)(smem + 12544);
    int*   segI1  = (int*)  (smem + 14592);
    int*   segI2  = (int*)  (smem + 16640);               // end 18688

    const int tid = threadIdx.x;
    const int wv  = tid >> 6;
    const int kh  = wv >> 2;
    const int rg  = wv & 3;
    const int lane = tid & 63;
    const int jb  = blockIdx.x;
    const int j0  = jb * 64;

    // stage hbr (64 KB) into LDS, coalesced
#pragma unroll
    for (int e = 0; e < 8; e++) {
        const int idx = tid + e * 512;      // 0..4095 float4s
        ((float4*)Bs)[idx] = ((const float4*)hbr)[idx];
    }
    __syncthreads();

    const unsigned short* Ab = Whr + ((size_t)(jb * 4 + rg) * 32 * 64) * 8;

    f32x4 acc0 = {0.f, 0.f, 0.f, 0.f};
    f32x4 acc1 = {0.f, 0.f, 0.f, 0.f};

#pragma unroll 4
    for (int i = 0; i < 16; i++) {
        const int kb = kh * 16 + i;
        const bf16x8 Av = *(const bf16x8*)(Ab + ((size_t)kb * 64 + lane) * 8);
        const bf16x8 B0 = *(const bf16x8*)(Bs + (((size_t)kb) * 64 + lane) * 8);
        const bf16x8 B1 = *(const bf16x8*)(Bs + (((size_t)(32 + kb)) * 64 + lane) * 8);
        acc0 = __builtin_amdgcn_mfma_f32_16x16x32_bf16(Av, B0, acc0, 0, 0, 0);
        acc1 = __builtin_amdgcn_mfma_f32_16x16x32_bf16(Av, B1, acc1, 0, 0, 0);
    }
    __syncthreads();   // Bs dead; logits may now alias it

    const int rbase = rg * 16 + (lane >> 4) * 4;
    const int bcol  = lane & 15;
    if (kh == 0) {
#pragma unroll
        for (int r = 0; r < 4; r++) {
            const int rw = rbase + r;
            logits[rw * 33 + bcol]      = acc0[r] + bfc[j0 + rw];
            logits[rw * 33 + 16 + bcol] = acc1[r];
        }
    }
    __syncthreads();
    if (kh == 1) {
#pragma unroll
        for (int r = 0; r < 4; r++) {
            const int rw = rbase + r;
            logits[rw * 33 + bcol]      += acc0[r];
            logits[rw * 33 + 16 + bcol] += acc1[r] + bfc[j0 + rw];
        }
    }
    __syncthreads();

    {
        const int b = tid & 31, seg = tid >> 5;
        float ls = 0.f, m1 = -1e30f, m2 = -1e30f;
        int i1 = 0x7fffffff, i2 = 0x7fffffff;
#pragma unroll
        for (int i = 0; i < 4; i++) {
            const int rw = seg * 4 + i;
            const float l = logits[rw * 33 + b];
            ls += expf(l);
            ins2(l, j0 + rw, m1, i1, m2, i2);
        }
        segS[seg * 32 + b] = ls;
        segM1[seg * 32 + b] = m1; segI1[seg * 32 + b] = i1;
        segM2[seg * 32 + b] = m2; segI2[seg * 32 + b] = i2;
    }
    __syncthreads();
    if (tid < 32) {
        const int b = tid;
        float ts = 0.f, m1 = -1e30f, m2 = -1e30f;
        int i1 = 0x7fffffff, i2 = 0x7fffffff;
#pragma unroll
        for (int seg = 0; seg < 16; seg++) {
            ts += segS[seg * 32 + b];
            ins2(segM1[seg * 32 + b], segI1[seg * 32 + b], m1, i1, m2, i2);
            ins2(segM2[seg * 32 + b], segI2[seg * 32 + b], m1, i1, m2, i2);
        }
        psum[b * NFM + jb] = ts;
        pm1[b * NFM + jb] = m1; pi1[b * NFM + jb] = i1;
        pm2[b * NFM + jb] = m2; pi2[b * NFM + jb] = i2;
        const int tgt = x[b * XROW + t + 1];
        const int loc = tgt - j0;
        if (loc >= 0 && loc < 64) lt[b] = logits[loc * 33 + b];
    }
}

// ---------------- finalize + guard + next embedding (+x planes) ------------
__global__ __launch_bounds__(512) void k_fin2(
    const float* __restrict__ psum, const float* __restrict__ pm1,
    const float* __restrict__ pm2, const int* __restrict__ pi1,
    const int* __restrict__ pi2, const float* __restrict__ lt,
    const float* __restrict__ h1, const float* __restrict__ Wfc,
    const float* __restrict__ bfc, const float* __restrict__ emb,
    float* __restrict__ xcur, unsigned short* __restrict__ xHi,
    unsigned short* __restrict__ xMid, float* __restrict__ out, int t)
{
    __shared__ float ss[512], sm1[512], sm2[512];
    __shared__ int si1[512], si2[512];
    __shared__ int sW, sA, sB2, sNeed;
    const int b = blockIdx.x, tid = threadIdx.x;

    const bool v = (tid < NFM);
    ss[tid]  = v ? psum[b * NFM + tid] : 0.f;
    sm1[tid] = v ? pm1[b * NFM + tid] : -1e30f;
    sm2[tid] = v ? pm2[b * NFM + tid] : -1e30f;
    si1[tid] = v ? pi1[b * NFM + tid] : 0x7fffffff;
    si2[tid] = v ? pi2[b * NFM + tid] : 0x7fffffff;
    __syncthreads();
    for (int s = 256; s > 0; s >>= 1) {
        if (tid < s) {
            ss[tid] += ss[tid + s];
            float a1 = sm1[tid], a2 = sm2[tid];
            int x1 = si1[tid], x2 = si2[tid];
            ins2(sm1[tid + s], si1[tid + s], a1, x1, a2, x2);
            ins2(sm2[tid + s], si2[tid + s], a1, x1, a2, x2);
            sm1[tid] = a1; si1[tid] = x1; sm2[tid] = a2; si2[tid] = x2;
        }
        __syncthreads();
    }
    if (tid == 0) {
        out[(size_t)b * TS + t] = expf(lt[b]) / ss[0];
        sW = si1[0]; sA = si1[0]; sB2 = si2[0];
        sNeed = (sm1[0] - sm2[0] < GAPT) ? 1 : 0;
    }
    __syncthreads();

    if (sNeed) {
        const int ia = sA, ib = sB2;
        float a1 = 0.f, a2 = 0.f;
        if (tid < 256) {
            const float4 hv = ((const float4*)(h1 + (size_t)b * HID))[tid];
            const float4 w1 = ((const float4*)(Wfc + (size_t)ia * HID))[tid];
            const float4 w2 = ((const float4*)(Wfc + (size_t)ib * HID))[tid];
            a1 = hv.x * w1.x + hv.y * w1.y + hv.z * w1.z + hv.w * w1.w;
            a2 = hv.x * w2.x + hv.y * w2.y + hv.z * w2.z + hv.w * w2.w;
        }
        __syncthreads();
        sm1[tid] = a1; sm2[tid] = a2;
        __syncthreads();
        for (int s = 128; s > 0; s >>= 1) {
            if (tid < s) { sm1[tid] += sm1[tid + s]; sm2[tid] += sm2[tid + s]; }
            __syncthreads();
        }
        if (tid == 0) {
            const float l1 = sm1[0] + bfc[ia];
            const float l2 = sm2[0] + bfc[ib];
            if (l2 > l1 || (l2 == l1 && ib < ia)) sW = ib;
        }
        __syncthreads();
    }
    if (tid < 256) {
        const float4 ev = ((const float4*)(emb + (size_t)sW * EMBD))[tid];
        ((float4*)(xcur + (size_t)b * EMBD))[tid] = ev;
        const int jh0 = tid * 4;
        const size_t p0 = pidx_act(b, jh0);
        const float e4[4] = {ev.x, ev.y, ev.z, ev.w};
#pragma unroll
        for (int q = 0; q < 4; q++) {
            const unsigned short h = f2bu(e4[q]);
            xHi[p0 + q]  = h;
            xMid[p0 + q] = f2bu(e4[q] - b2f(h));
        }
    }
}

// ================= R14-tier fallback kernels (f32 gates) =================

__global__ __launch_bounds__(256) void k_init(
    const int* __restrict__ x, const float* __restrict__ emb,
    float* __restrict__ xcur, float* __restrict__ st)
{
    const int b = blockIdx.x, tid = threadIdx.x;
    float4 z = {0.f, 0.f, 0.f, 0.f};
#pragma unroll
    for (int q = 0; q < 4; q++)
        ((float4*)(st + (size_t)q * B * HID + (size_t)b * HID))[tid] = z;
    const int tok = x[b * XROW];
    ((float4*)(xcur + (size_t)b * EMBD))[tid] =
        ((const float4*)(emb + (size_t)tok * EMBD))[tid];
}

__global__ __launch_bounds__(512) void k_layer(
    const float* __restrict__ xin, const float* __restrict__ hin,
    const float* __restrict__ Wih, const float* __restrict__ Whh,
    float* __restrict__ gpart)
{
    __shared__ float4 sb4x[2048];
    const int tid = threadIdx.x;
    const int ww  = tid >> 6;
    const int lane = tid & 63;
    const int rs  = lane >> 2;
    const int kq  = lane & 3;
    const int jb  = blockIdx.x;
    const int ks  = blockIdx.y;
    const bool xpart = (ks < 4);
    const float* __restrict__ src = xpart ? xin : hin;
    const float* __restrict__ Wb  = xpart ? Wih : Whh;
    const int cchunk = (ks & 3) * 64;

#pragma unroll
    for (int e = 0; e < 4; e++) {
        const int fi = tid + e * 512;
        const int b = fi >> 6, off = fi & 63;
        sb4x[fi] = ((const float4*)(src + (size_t)b * 1024))[cchunk + off];
    }
    __syncthreads();

    const int j0 = jb * 128;
    const float4* W4 = (const float4*)Wb;
    const float4* wp[8];
#pragma unroll
    for (int jj = 0; jj < 8; jj++)
        wp[jj] = W4 + (size_t)(j0 + rs * 8 + jj) * 256 + cchunk;

    float acc[8][4];
#pragma unroll
    for (int jj = 0; jj < 8; jj++)
#pragma unroll
        for (int bl = 0; bl < 4; bl++) acc[jj][bl] = 0.f;

#pragma unroll 4
    for (int s = 0; s < 16; s++) {
        const int col = s * 4 + kq;
        float4 w[8];
#pragma unroll
        for (int jj = 0; jj < 8; jj++) w[jj] = wp[jj][col];
#pragma unroll
        for (int bl = 0; bl < 4; bl++) {
            const float4 xv = sb4x[(ww * 4 + bl) * 64 + col];
#pragma unroll
            for (int jj = 0; jj < 8; jj++) FMA4(acc[jj][bl], w[jj], xv);
        }
    }

#pragma unroll
    for (int jj = 0; jj < 8; jj++)
#pragma unroll
        for (int bl = 0; bl < 4; bl++) {
            acc[jj][bl] += __shfl_xor(acc[jj][bl], 1);
            acc[jj][bl] += __shfl_xor(acc[jj][bl], 2);
        }

#pragma unroll
    for (int q = 0; q < 2; q++) {
        const int jjw = 2 * kq + q;
        const int r = j0 + rs * 8 + jjw;
#pragma unroll
        for (int bl = 0; bl < 4; bl++) {
            const int b = ww * 4 + bl;
            float v = acc[0][bl];
#pragma unroll
            for (int jj = 1; jj < 8; jj++)
                if (jjw == jj) v = acc[jj][bl];
            gpart[((size_t)ks * B + b) * G + r] = v;
        }
    }
}

__global__ __launch_bounds__(256) void k_act(
    const float* __restrict__ part, const float* __restrict__ bih,
    const float* __restrict__ bhh, float* __restrict__ c, float* __restrict__ h,
    unsigned short* __restrict__ hbr)
{
    const int idx = blockIdx.x * 256 + threadIdx.x;
    const int b = idx >> 10, jh = idx & 1023;
    float gi = bih[jh]        + bhh[jh];
    float gf = bih[jh + 1024] + bhh[jh + 1024];
    float gg = bih[jh + 2048] + bhh[jh + 2048];
    float go = bih[jh + 3072] + bhh[jh + 3072];
#pragma unroll
    for (int ks = 0; ks < KSL; ks++) {
        const float* p = part + ((size_t)ks * B + b) * G;
        gi += p[jh]; gf += p[jh + 1024]; gg += p[jh + 2048]; go += p[jh + 3072];
    }
    const float i = 1.f / (1.f + expf(-gi));
    const float f = 1.f / (1.f + expf(-gf));
    const float g = tanhf(gg);
    const float o = 1.f / (1.f + expf(-go));
    const float cn = f * c[idx] + i * g;
    c[idx] = cn;
    const float hv = o * tanhf(cn);
    h[idx] = hv;
    hbr[pidx_act(b, jh)] = f2bu(hv);
}

// ================= launch =================

extern "C" void kernel_launch(void* const* d_in, const int* in_sizes, int n_in,
                              void* d_out, int out_size, void* d_ws, size_t ws_size,
                              hipStream_t stream)
{
    const int*   x   = (const int*)  d_in[0];
    const float* emb = (const float*)d_in[1];
    const float* Wih = (const float*)d_in[2];
    const float* Whh = (const float*)d_in[3];
    const float* bih = (const float*)d_in[4];
    const float* bhh = (const float*)d_in[5];
    const float* Wfc = (const float*)d_in[6];
    const float* bfc = (const float*)d_in[7];
    float* out = (float*)d_out;
    float* ws = (float*)d_ws;

    // layout (float slots) — R15-compatible
    const size_t o_xcur = 0;
    const size_t o_st   = 32768;
    const size_t o_gp   = 163840;
    const size_t o_ps   = 1212416;
    const size_t o_m1   = 1228416;
    const size_t o_m2   = 1244416;
    const size_t o_i1   = 1260416;
    const size_t o_i2   = 1276416;
    const size_t o_lt   = 1292416;
    const size_t o_hbr  = 1292448;
    const size_t o_whr  = 1308832;
    const size_t NEED_FC = (size_t)(1308832 + 16384000) * 4;
    const size_t o_pl   = 17692832;
    const size_t o_gw   = o_pl + 6 * 8192;
    const size_t o_cnt  = o_gw + 16777216;
    const size_t NEED_ALL = (o_cnt + 128) * 4;

    float* xcur = ws + o_xcur;
    float* h0 = ws + o_st, *h1 = h0 + 32768, *c0 = h1 + 32768, *c1 = c0 + 32768;
    float* gpart = ws + o_gp;
    float* psum = ws + o_ps;
    float* pm1  = ws + o_m1;
    float* pm2  = ws + o_m2;
    int*   pi1  = (int*)(ws + o_i1);
    int*   pi2  = (int*)(ws + o_i2);
    float* lt   = ws + o_lt;
    unsigned short* hbr = (unsigned short*)(ws + o_hbr);
    unsigned short* Whr = (unsigned short*)(ws + o_whr);
    unsigned short* xHi   = (unsigned short*)(ws + o_pl);
    unsigned short* xMid  = xHi + 32768;
    unsigned short* h0Hi  = xMid + 32768;
    unsigned short* h0Mid = h0Hi + 32768;
    unsigned short* h1Hi  = h0Mid + 32768;
    unsigned short* h1Mid = h1Hi + 32768;
    unsigned short* Gw = (unsigned short*)(ws + o_gw);
    unsigned short* gw2[2][2];
    for (int L = 0; L < 2; L++)
        for (int p = 0; p < 2; p++)
            gw2[L][p] = Gw + ((size_t)L * 2 + p) * (2 * GWM);

    const size_t G4 = (size_t)G;
    const bool fc_ok  = (ws_size >= NEED_FC);
    const bool all_ok = (ws_size >= NEED_ALL);

    if (fc_ok)
        k_conv<<<4096, 256, 0, stream>>>(Wfc, Whr);

    if (all_ok) {
        k_conv_g2<<<4096, 256, 0, stream>>>(Wih, Whh, gw2[0][0], gw2[0][1]);
        k_conv_g2<<<4096, 256, 0, stream>>>(Wih + G4 * EMBD, Whh + G4 * HID,
                                            gw2[1][0], gw2[1][1]);
        k_init_m<<<B, 256, 0, stream>>>(x, emb, xcur, ws + o_st,
                                        xHi, xMid, h0Hi, h0Mid, h1Hi, h1Mid);
        for (int t = 0; t < TS; t++) {
            k_layer_f<<<256, 1024, 0, stream>>>(
                gw2[0][0], gw2[0][1], xHi, xMid, h0Hi, h0Mid,
                bih, bhh, c0, h0Hi, h0Mid, nullptr);
            k_layer_f<<<256, 1024, 0, stream>>>(
                gw2[1][0], gw2[1][1], h0Hi, h0Mid, h1Hi, h1Mid,
                bih + G, bhh + G, c1, h1Hi, h1Mid, h1);
            k_fc_mfma<<<NFM, 512, 0, stream>>>(Whr, h1Hi, bfc, x, t,
                                               psum, pm1, pm2, pi1, pi2, lt);
            k_fin2<<<B, 512, 0, stream>>>(psum, pm1, pm2, pi1, pi2, lt,
                                          h1, Wfc, bfc, emb, xcur,
                                          xHi, xMid, out, t);
        }
        return;
    }

    // ---- R14 tier: f32 gates + MFMA FC + separate fin ----
    k_init<<<B, 256, 0, stream>>>(x, emb, xcur, ws + o_st);
    for (int t = 0; t < TS; t++) {
        k_layer<<<dim3(32, KSL), 512, 0, stream>>>(xcur, h0, Wih, Whh, gpart);
        k_act<<<128, 256, 0, stream>>>(gpart, bih, bhh, c0, h0, hbr);
        k_layer<<<dim3(32, KSL), 512, 0, stream>>>(h0, h1, Wih + G4 * EMBD,
                                                   Whh + G4 * HID, gpart);
        k_act<<<128, 256, 0, stream>>>(gpart, bih + G, bhh + G, c1, h1, hbr);
        k_fc_mfma<<<NFM, 512, 0, stream>>>(Whr, hbr, bfc, x, t,
                                           psum, pm1, pm2, pi1, pi2, lt);
        k_fin2<<<B, 512, 0, stream>>>(psum, pm1, pm2, pi1, pi2, lt,
                                      h1, Wfc, bfc, emb, xcur,
                                      hbr, hbr, out, t);
    }
}

// Round 20
// 6528.373 us; speedup vs baseline: 6.0495x; 1.0175x over previous
//
#include <hip/hip_runtime.h>
#include <hip/hip_bf16.h>
#include <math.h>

#define B    32
#define EMBD 1024
#define HID  1024
#define G    4096
#define V    32000
#define TS   128
#define XROW (TS + 1)
#define KSL  8
#define NFM  500
#define GAPT 2e-3f
#define GWM  (4096 * 1024)

typedef short bf16x8 __attribute__((ext_vector_type(8)));
typedef float f32x4  __attribute__((ext_vector_type(4)));

#define FMA4(acc, W_, V_) \
  acc = fmaf((W_).x,(V_).x, fmaf((W_).y,(V_).y, fmaf((W_).z,(V_).z, fmaf((W_).w,(V_).w,(acc)))))

__device__ __forceinline__ unsigned short f2bu(float x) {
    __hip_bfloat16 b = __float2bfloat16(x);
    return *reinterpret_cast<unsigned short*>(&b);
}
__device__ __forceinline__ float b2f(unsigned short u) {
    union { unsigned int v; float f; } c; c.v = ((unsigned int)u) << 16; return c.f;
}
__device__ __forceinline__ void ins2(float m, int i, float& m1, int& i1,
                                     float& m2, int& i2) {
    if (m > m1 || (m == m1 && i < i1)) { m2 = m1; i2 = i1; m1 = m; i1 = i; }
    else if (m > m2 || (m == m2 && i < i2)) { m2 = m; i2 = i; }
}
__device__ __forceinline__ size_t pidx_act(int b, int jh) {
    const int kb = jh >> 5, kslot = (jh >> 3) & 3, e = jh & 7;
    const int lane = kslot * 16 + (b & 15);
    return ((((size_t)(b >> 4)) * 32 + kb) * 64 + lane) * 8 + e;
}

// ---------------- FC weight bf16 fragment-major reorder (R14-verified) -----
__global__ __launch_bounds__(256) void k_conv(
    const float* __restrict__ W, unsigned short* __restrict__ out)
{
    const int ngrp = V * HID / 8;
    for (int o = blockIdx.x * 256 + threadIdx.x; o < ngrp; o += gridDim.x * 256) {
        const int lane = o & 63, kb = (o >> 6) & 31, tile = o >> 11;
        const int row = tile * 16 + (lane & 15);
        const int k0  = kb * 32 + (lane >> 4) * 8;
        const float4 v0 = *(const float4*)(W + (size_t)row * 1024 + k0);
        const float4 v1 = *(const float4*)(W + (size_t)row * 1024 + k0 + 4);
        ushort4 a, b;
        a.x = f2bu(v0.x); a.y = f2bu(v0.y); a.z = f2bu(v0.z); a.w = f2bu(v0.w);
        b.x = f2bu(v1.x); b.y = f2bu(v1.y); b.z = f2bu(v1.z); b.w = f2bu(v1.w);
        ((ushort4*)out)[o * 2]     = a;
        ((ushort4*)out)[o * 2 + 1] = b;
    }
}

// ---------------- gate weights: concat-K, act-grouped tiles (R17-verified) --
__global__ __launch_bounds__(256) void k_conv_g2(
    const float* __restrict__ Wih, const float* __restrict__ Whh,
    unsigned short* __restrict__ hi, unsigned short* __restrict__ mid)
{
    const int ngrp = 256 * 64 * 64;
    for (int o = blockIdx.x * 256 + threadIdx.x; o < ngrp; o += gridDim.x * 256) {
        const int lane = o & 63, kbg = (o >> 6) & 63, tile = o >> 12;
        const int ir = lane & 15;
        const int gate = ir >> 2, jr = ir & 3;
        const int row = gate * 1024 + tile * 4 + jr;
        const bool xp = (kbg < 32);
        const float* src = xp ? Wih : Whh;
        const int kbl = xp ? kbg : (kbg - 32);
        const int k0 = kbl * 32 + (lane >> 4) * 8;
#pragma unroll
        for (int q = 0; q < 2; q++) {
            const float4 v = *(const float4*)(src + (size_t)row * 1024 + k0 + q * 4);
            ushort4 h, m;
            h.x = f2bu(v.x); m.x = f2bu(v.x - b2f(h.x));
            h.y = f2bu(v.y); m.y = f2bu(v.y - b2f(h.y));
            h.z = f2bu(v.z); m.z = f2bu(v.z - b2f(h.z));
            h.w = f2bu(v.w); m.w = f2bu(v.w - b2f(h.w));
            ((ushort4*)hi)[o * 2 + q]  = h;
            ((ushort4*)mid)[o * 2 + q] = m;
        }
    }
}

// ---------------- init (mfma tier): states=0, planes ----------------
__global__ __launch_bounds__(256) void k_init_m(
    const int* __restrict__ x, const float* __restrict__ emb,
    float* __restrict__ xcur, float* __restrict__ st,
    unsigned short* __restrict__ xHi, unsigned short* __restrict__ xMid,
    unsigned short* __restrict__ h0Hi, unsigned short* __restrict__ h0Mid,
    unsigned short* __restrict__ h1Hi, unsigned short* __restrict__ h1Mid)
{
    const int b = blockIdx.x, tid = threadIdx.x;
    float4 z = {0.f, 0.f, 0.f, 0.f};
#pragma unroll
    for (int q = 0; q < 4; q++)
        ((float4*)(st + (size_t)q * B * HID + (size_t)b * HID))[tid] = z;
    const int tok = x[b * XROW];
    const float4 ev = ((const float4*)(emb + (size_t)tok * EMBD))[tid];
    ((float4*)(xcur + (size_t)b * EMBD))[tid] = ev;
    const int jh0 = tid * 4;
    const size_t p0 = pidx_act(b, jh0);
    const float e4[4] = {ev.x, ev.y, ev.z, ev.w};
#pragma unroll
    for (int q = 0; q < 4; q++) {
        const unsigned short h = f2bu(e4[q]);
        xHi[p0 + q]  = h;
        xMid[p0 + q] = f2bu(e4[q] - b2f(h));
        h0Hi[p0 + q] = 0; h0Mid[p0 + q] = 0;
        h1Hi[p0 + q] = 0; h1Mid[p0 + q] = 0;
    }
}

// ---------------- fused gates GEMM + in-block act (16-wave, R18-verified) ---
__global__ __launch_bounds__(1024) void k_layer_f(
    const unsigned short* __restrict__ Ahi, const unsigned short* __restrict__ Amid,
    const unsigned short* __restrict__ xHi, const unsigned short* __restrict__ xMid,
    const unsigned short* __restrict__ hHi, const unsigned short* __restrict__ hMid,
    const float* __restrict__ bih, const float* __restrict__ bhh,
    float* __restrict__ c2,
    unsigned short* __restrict__ oHi, unsigned short* __restrict__ oMid,
    float* __restrict__ h_f32)
{
    __shared__ float red[16 * 16 * 33];     // 33.8 KB
    const int tid = threadIdx.x;
    const int wv  = tid >> 6;               // 0..15 (k-chunk)
    const int lane = tid & 63;
    const int jq  = blockIdx.x;             // 0..255
    const bool xp = (wv < 8);
    const unsigned short* Bh = xp ? xHi : hHi;
    const unsigned short* Bm = xp ? xMid : hMid;
    const int kbl0 = xp ? (wv * 4) : ((wv - 8) * 4);

    f32x4 acc0 = {0.f, 0.f, 0.f, 0.f};
    f32x4 acc1 = {0.f, 0.f, 0.f, 0.f};

#pragma unroll
    for (int i = 0; i < 4; i++) {
        const int kbg = wv * 4 + i;
        const int kbl = kbl0 + i;
        const size_t aoff = (((size_t)jq * 64 + kbg) * 64 + lane) * 8;
        const bf16x8 Avh = *(const bf16x8*)(Ahi + aoff);
        const bf16x8 Avm = *(const bf16x8*)(Amid + aoff);
        const size_t b0off = (((size_t)kbl) * 64 + lane) * 8;
        const size_t b1off = (((size_t)(32 + kbl)) * 64 + lane) * 8;
        const bf16x8 B0h = *(const bf16x8*)(Bh + b0off);
        const bf16x8 B0m = *(const bf16x8*)(Bm + b0off);
        const bf16x8 B1h = *(const bf16x8*)(Bh + b1off);
        const bf16x8 B1m = *(const bf16x8*)(Bm + b1off);
        acc0 = __builtin_amdgcn_mfma_f32_16x16x32_bf16(Avh, B0h, acc0, 0, 0, 0);
        acc1 = __builtin_amdgcn_mfma_f32_16x16x32_bf16(Avh, B1h, acc1, 0, 0, 0);
        acc0 = __builtin_amdgcn_mfma_f32_16x16x32_bf16(Avh, B0m, acc0, 0, 0, 0);
        acc1 = __builtin_amdgcn_mfma_f32_16x16x32_bf16(Avh, B1m, acc1, 0, 0, 0);
        acc0 = __builtin_amdgcn_mfma_f32_16x16x32_bf16(Avm, B0h, acc0, 0, 0, 0);
        acc1 = __builtin_amdgcn_mfma_f32_16x16x32_bf16(Avm, B1h, acc1, 0, 0, 0);
    }

    {
        const int bcol = lane & 15;
#pragma unroll
        for (int r = 0; r < 4; r++) {
            const int rd = (lane >> 4) * 4 + r;
            red[(wv * 16 + rd) * 33 + bcol]      = acc0[r];
            red[(wv * 16 + rd) * 33 + 16 + bcol] = acc1[r];
        }
    }
    __syncthreads();

    if (tid < 128) {
        const int jr = tid >> 5, b = tid & 31;
        const int jh = jq * 4 + jr;
        float gs[4];
#pragma unroll
        for (int g = 0; g < 4; g++) {
            const int rd = g * 4 + jr;
            float v = 0.f;
#pragma unroll
            for (int w = 0; w < 16; w++)
                v += red[(w * 16 + rd) * 33 + b];
            gs[g] = v + bih[g * 1024 + jh] + bhh[g * 1024 + jh];
        }
        const float i = 1.f / (1.f + expf(-gs[0]));
        const float f = 1.f / (1.f + expf(-gs[1]));
        const float g = tanhf(gs[2]);
        const float o = 1.f / (1.f + expf(-gs[3]));
        const int ci = jh * 32 + b;
        const float cn = f * c2[ci] + i * g;
        c2[ci] = cn;
        const float hv = o * tanhf(cn);
        if (h_f32) h_f32[(size_t)b * HID + jh] = hv;
        const size_t p = pidx_act(b, jh);
        const unsigned short uh = f2bu(hv);
        oHi[p]  = uh;
        oMid[p] = f2bu(hv - b2f(uh));
    }
}

// ---------------- MFMA FC v5: full A-prefetch + B in LDS --------------------
// grid 500, block 512 = 8 waves (2 kh x 4 rg). Block: 64 rows x 32 b.
__global__ __launch_bounds__(512, 4) void k_fc_mfma(
    const unsigned short* __restrict__ Whr, const unsigned short* __restrict__ hbr,
    const float* __restrict__ bfc, const int* __restrict__ x, int t,
    float* __restrict__ psum, float* __restrict__ pm1, float* __restrict__ pm2,
    int* __restrict__ pi1, int* __restrict__ pi2, float* __restrict__ lt)
{
    __shared__ char smem[65536];            // union: Bs (64 KB) / logits+segs
    unsigned short* Bs = (unsigned short*)smem;
    float* logits = (float*)smem;
    float* segS   = (float*)(smem + 8448);
    float* segM1  = (float*)(smem + 10496);
    float* segM2  = (float*)(smem + 12544);
    int*   segI1  = (int*)  (smem + 14592);
    int*   segI2  = (int*)  (smem + 16640);

    const int tid = threadIdx.x;
    const int wv  = tid >> 6;
    const int kh  = wv >> 2;
    const int rg  = wv & 3;
    const int lane = tid & 63;
    const int jb  = blockIdx.x;
    const int j0  = jb * 64;

    const unsigned short* Ab = Whr + ((size_t)(jb * 4 + rg) * 32 * 64) * 8;

    // issue ALL 16 A-fragment loads first (64 VGPR, 16 outstanding)
    bf16x8 Areg[16];
#pragma unroll
    for (int i = 0; i < 16; i++) {
        const int kb = kh * 16 + i;
        Areg[i] = *(const bf16x8*)(Ab + ((size_t)kb * 64 + lane) * 8);
    }

    // stage hbr (64 KB) into LDS, coalesced (interleaves with A loads)
#pragma unroll
    for (int e = 0; e < 8; e++) {
        const int idx = tid + e * 512;
        ((float4*)Bs)[idx] = ((const float4*)hbr)[idx];
    }
    __syncthreads();

    f32x4 acc0 = {0.f, 0.f, 0.f, 0.f};
    f32x4 acc1 = {0.f, 0.f, 0.f, 0.f};

#pragma unroll
    for (int i = 0; i < 16; i++) {
        const int kb = kh * 16 + i;
        const bf16x8 B0 = *(const bf16x8*)(Bs + (((size_t)kb) * 64 + lane) * 8);
        const bf16x8 B1 = *(const bf16x8*)(Bs + (((size_t)(32 + kb)) * 64 + lane) * 8);
        acc0 = __builtin_amdgcn_mfma_f32_16x16x32_bf16(Areg[i], B0, acc0, 0, 0, 0);
        acc1 = __builtin_amdgcn_mfma_f32_16x16x32_bf16(Areg[i], B1, acc1, 0, 0, 0);
    }
    __syncthreads();   // Bs dead; logits may now alias it

    const int rbase = rg * 16 + (lane >> 4) * 4;
    const int bcol  = lane & 15;
    if (kh == 0) {
#pragma unroll
        for (int r = 0; r < 4; r++) {
            const int rw = rbase + r;
            logits[rw * 33 + bcol]      = acc0[r] + bfc[j0 + rw];
            logits[rw * 33 + 16 + bcol] = acc1[r];
        }
    }
    __syncthreads();
    if (kh == 1) {
#pragma unroll
        for (int r = 0; r < 4; r++) {
            const int rw = rbase + r;
            logits[rw * 33 + bcol]      += acc0[r];
            logits[rw * 33 + 16 + bcol] += acc1[r] + bfc[j0 + rw];
        }
    }
    __syncthreads();

    {
        const int b = tid & 31, seg = tid >> 5;
        float ls = 0.f, m1 = -1e30f, m2 = -1e30f;
        int i1 = 0x7fffffff, i2 = 0x7fffffff;
#pragma unroll
        for (int i = 0; i < 4; i++) {
            const int rw = seg * 4 + i;
            const float l = logits[rw * 33 + b];
            ls += expf(l);
            ins2(l, j0 + rw, m1, i1, m2, i2);
        }
        segS[seg * 32 + b] = ls;
        segM1[seg * 32 + b] = m1; segI1[seg * 32 + b] = i1;
        segM2[seg * 32 + b] = m2; segI2[seg * 32 + b] = i2;
    }
    __syncthreads();
    if (tid < 32) {
        const int b = tid;
        float ts = 0.f, m1 = -1e30f, m2 = -1e30f;
        int i1 = 0x7fffffff, i2 = 0x7fffffff;
#pragma unroll
        for (int seg = 0; seg < 16; seg++) {
            ts += segS[seg * 32 + b];
            ins2(segM1[seg * 32 + b], segI1[seg * 32 + b], m1, i1, m2, i2);
            ins2(segM2[seg * 32 + b], segI2[seg * 32 + b], m1, i1, m2, i2);
        }
        psum[b * NFM + jb] = ts;
        pm1[b * NFM + jb] = m1; pi1[b * NFM + jb] = i1;
        pm2[b * NFM + jb] = m2; pi2[b * NFM + jb] = i2;
        const int tgt = x[b * XROW + t + 1];
        const int loc = tgt - j0;
        if (loc >= 0 && loc < 64) lt[b] = logits[loc * 33 + b];
    }
}

// ---------------- finalize + guard + next embedding (+x planes) ------------
__global__ __launch_bounds__(512) void k_fin2(
    const float* __restrict__ psum, const float* __restrict__ pm1,
    const float* __restrict__ pm2, const int* __restrict__ pi1,
    const int* __restrict__ pi2, const float* __restrict__ lt,
    const float* __restrict__ h1, const float* __restrict__ Wfc,
    const float* __restrict__ bfc, const float* __restrict__ emb,
    float* __restrict__ xcur, unsigned short* __restrict__ xHi,
    unsigned short* __restrict__ xMid, float* __restrict__ out, int t)
{
    __shared__ float ss[512], sm1[512], sm2[512];
    __shared__ int si1[512], si2[512];
    __shared__ int sW, sA, sB2, sNeed;
    const int b = blockIdx.x, tid = threadIdx.x;

    const bool v = (tid < NFM);
    ss[tid]  = v ? psum[b * NFM + tid] : 0.f;
    sm1[tid] = v ? pm1[b * NFM + tid] : -1e30f;
    sm2[tid] = v ? pm2[b * NFM + tid] : -1e30f;
    si1[tid] = v ? pi1[b * NFM + tid] : 0x7fffffff;
    si2[tid] = v ? pi2[b * NFM + tid] : 0x7fffffff;
    __syncthreads();
    for (int s = 256; s > 0; s >>= 1) {
        if (tid < s) {
            ss[tid] += ss[tid + s];
            float a1 = sm1[tid], a2 = sm2[tid];
            int x1 = si1[tid], x2 = si2[tid];
            ins2(sm1[tid + s], si1[tid + s], a1, x1, a2, x2);
            ins2(sm2[tid + s], si2[tid + s], a1, x1, a2, x2);
            sm1[tid] = a1; si1[tid] = x1; sm2[tid] = a2; si2[tid] = x2;
        }
        __syncthreads();
    }
    if (tid == 0) {
        out[(size_t)b * TS + t] = expf(lt[b]) / ss[0];
        sW = si1[0]; sA = si1[0]; sB2 = si2[0];
        sNeed = (sm1[0] - sm2[0] < GAPT) ? 1 : 0;
    }
    __syncthreads();

    if (sNeed) {
        const int ia = sA, ib = sB2;
        float a1 = 0.f, a2 = 0.f;
        if (tid < 256) {
            const float4 hv = ((const float4*)(h1 + (size_t)b * HID))[tid];
            const float4 w1 = ((const float4*)(Wfc + (size_t)ia * HID))[tid];
            const float4 w2 = ((const float4*)(Wfc + (size_t)ib * HID))[tid];
            a1 = hv.x * w1.x + hv.y * w1.y + hv.z * w1.z + hv.w * w1.w;
            a2 = hv.x * w2.x + hv.y * w2.y + hv.z * w2.z + hv.w * w2.w;
        }
        __syncthreads();
        sm1[tid] = a1; sm2[tid] = a2;
        __syncthreads();
        for (int s = 128; s > 0; s >>= 1) {
            if (tid < s) { sm1[tid] += sm1[tid + s]; sm2[tid] += sm2[tid + s]; }
            __syncthreads();
        }
        if (tid == 0) {
            const float l1 = sm1[0] + bfc[ia];
            const float l2 = sm2[0] + bfc[ib];
            if (l2 > l1 || (l2 == l1 && ib < ia)) sW = ib;
        }
        __syncthreads();
    }
    if (tid < 256) {
        const float4 ev = ((const float4*)(emb + (size_t)sW * EMBD))[tid];
        ((float4*)(xcur + (size_t)b * EMBD))[tid] = ev;
        const int jh0 = tid * 4;
        const size_t p0 = pidx_act(b, jh0);
        const float e4[4] = {ev.x, ev.y, ev.z, ev.w};
#pragma unroll
        for (int q = 0; q < 4; q++) {
            const unsigned short h = f2bu(e4[q]);
            xHi[p0 + q]  = h;
            xMid[p0 + q] = f2bu(e4[q] - b2f(h));
        }
    }
}

// ================= R14-tier fallback kernels (f32 gates) =================

__global__ __launch_bounds__(256) void k_init(
    const int* __restrict__ x, const float* __restrict__ emb,
    float* __restrict__ xcur, float* __restrict__ st)
{
    const int b = blockIdx.x, tid = threadIdx.x;
    float4 z = {0.f, 0.f, 0.f, 0.f};
#pragma unroll
    for (int q = 0; q < 4; q++)
        ((float4*)(st + (size_t)q * B * HID + (size_t)b * HID))[tid] = z;
    const int tok = x[b * XROW];
    ((float4*)(xcur + (size_t)b * EMBD))[tid] =
        ((const float4*)(emb + (size_t)tok * EMBD))[tid];
}

__global__ __launch_bounds__(512) void k_layer(
    const float* __restrict__ xin, const float* __restrict__ hin,
    const float* __restrict__ Wih, const float* __restrict__ Whh,
    float* __restrict__ gpart)
{
    __shared__ float4 sb4x[2048];
    const int tid = threadIdx.x;
    const int ww  = tid >> 6;
    const int lane = tid & 63;
    const int rs  = lane >> 2;
    const int kq  = lane & 3;
    const int jb  = blockIdx.x;
    const int ks  = blockIdx.y;
    const bool xpart = (ks < 4);
    const float* __restrict__ src = xpart ? xin : hin;
    const float* __restrict__ Wb  = xpart ? Wih : Whh;
    const int cchunk = (ks & 3) * 64;

#pragma unroll
    for (int e = 0; e < 4; e++) {
        const int fi = tid + e * 512;
        const int b = fi >> 6, off = fi & 63;
        sb4x[fi] = ((const float4*)(src + (size_t)b * 1024))[cchunk + off];
    }
    __syncthreads();

    const int j0 = jb * 128;
    const float4* W4 = (const float4*)Wb;
    const float4* wp[8];
#pragma unroll
    for (int jj = 0; jj < 8; jj++)
        wp[jj] = W4 + (size_t)(j0 + rs * 8 + jj) * 256 + cchunk;

    float acc[8][4];
#pragma unroll
    for (int jj = 0; jj < 8; jj++)
#pragma unroll
        for (int bl = 0; bl < 4; bl++) acc[jj][bl] = 0.f;

#pragma unroll 4
    for (int s = 0; s < 16; s++) {
        const int col = s * 4 + kq;
        float4 w[8];
#pragma unroll
        for (int jj = 0; jj < 8; jj++) w[jj] = wp[jj][col];
#pragma unroll
        for (int bl = 0; bl < 4; bl++) {
            const float4 xv = sb4x[(ww * 4 + bl) * 64 + col];
#pragma unroll
            for (int jj = 0; jj < 8; jj++) FMA4(acc[jj][bl], w[jj], xv);
        }
    }

#pragma unroll
    for (int jj = 0; jj < 8; jj++)
#pragma unroll
        for (int bl = 0; bl < 4; bl++) {
            acc[jj][bl] += __shfl_xor(acc[jj][bl], 1);
            acc[jj][bl] += __shfl_xor(acc[jj][bl], 2);
        }

#pragma unroll
    for (int q = 0; q < 2; q++) {
        const int jjw = 2 * kq + q;
        const int r = j0 + rs * 8 + jjw;
#pragma unroll
        for (int bl = 0; bl < 4; bl++) {
            const int b = ww * 4 + bl;
            float v = acc[0][bl];
#pragma unroll
            for (int jj = 1; jj < 8; jj++)
                if (jjw == jj) v = acc[jj][bl];
            gpart[((size_t)ks * B + b) * G + r] = v;
        }
    }
}

__global__ __launch_bounds__(256) void k_act(
    const float* __restrict__ part, const float* __restrict__ bih,
    const float* __restrict__ bhh, float* __restrict__ c, float* __restrict__ h,
    unsigned short* __restrict__ hbr)
{
    const int idx = blockIdx.x * 256 + threadIdx.x;
    const int b = idx >> 10, jh = idx & 1023;
    float gi = bih[jh]        + bhh[jh];
    float gf = bih[jh + 1024] + bhh[jh + 1024];
    float gg = bih[jh + 2048] + bhh[jh + 2048];
    float go = bih[jh + 3072] + bhh[jh + 3072];
#pragma unroll
    for (int ks = 0; ks < KSL; ks++) {
        const float* p = part + ((size_t)ks * B + b) * G;
        gi += p[jh]; gf += p[jh + 1024]; gg += p[jh + 2048]; go += p[jh + 3072];
    }
    const float i = 1.f / (1.f + expf(-gi));
    const float f = 1.f / (1.f + expf(-gf));
    const float g = tanhf(gg);
    const float o = 1.f / (1.f + expf(-go));
    const float cn = f * c[idx] + i * g;
    c[idx] = cn;
    const float hv = o * tanhf(cn);
    h[idx] = hv;
    hbr[pidx_act(b, jh)] = f2bu(hv);
}

// ================= launch =================

extern "C" void kernel_launch(void* const* d_in, const int* in_sizes, int n_in,
                              void* d_out, int out_size, void* d_ws, size_t ws_size,
                              hipStream_t stream)
{
    const int*   x   = (const int*)  d_in[0];
    const float* emb = (const float*)d_in[1];
    const float* Wih = (const float*)d_in[2];
    const float* Whh = (const float*)d_in[3];
    const float* bih = (const float*)d_in[4];
    const float* bhh = (const float*)d_in[5];
    const float* Wfc = (const float*)d_in[6];
    const float* bfc = (const float*)d_in[7];
    float* out = (float*)d_out;
    float* ws = (float*)d_ws;

    // layout (float slots) — R15-compatible
    const size_t o_xcur = 0;
    const size_t o_st   = 32768;
    const size_t o_gp   = 163840;
    const size_t o_ps   = 1212416;
    const size_t o_m1   = 1228416;
    const size_t o_m2   = 1244416;
    const size_t o_i1   = 1260416;
    const size_t o_i2   = 1276416;
    const size_t o_lt   = 1292416;
    const size_t o_hbr  = 1292448;
    const size_t o_whr  = 1308832;
    const size_t NEED_FC = (size_t)(1308832 + 16384000) * 4;
    const size_t o_pl   = 17692832;
    const size_t o_gw   = o_pl + 6 * 8192;
    const size_t o_cnt  = o_gw + 16777216;
    const size_t NEED_ALL = (o_cnt + 128) * 4;

    float* xcur = ws + o_xcur;
    float* h0 = ws + o_st, *h1 = h0 + 32768, *c0 = h1 + 32768, *c1 = c0 + 32768;
    float* gpart = ws + o_gp;
    float* psum = ws + o_ps;
    float* pm1  = ws + o_m1;
    float* pm2  = ws + o_m2;
    int*   pi1  = (int*)(ws + o_i1);
    int*   pi2  = (int*)(ws + o_i2);
    float* lt   = ws + o_lt;
    unsigned short* hbr = (unsigned short*)(ws + o_hbr);
    unsigned short* Whr = (unsigned short*)(ws + o_whr);
    unsigned short* xHi   = (unsigned short*)(ws + o_pl);
    unsigned short* xMid  = xHi + 32768;
    unsigned short* h0Hi  = xMid + 32768;
    unsigned short* h0Mid = h0Hi + 32768;
    unsigned short* h1Hi  = h0Mid + 32768;
    unsigned short* h1Mid = h1Hi + 32768;
    unsigned short* Gw = (unsigned short*)(ws + o_gw);
    unsigned short* gw2[2][2];
    for (int L = 0; L < 2; L++)
        for (int p = 0; p < 2; p++)
            gw2[L][p] = Gw + ((size_t)L * 2 + p) * (2 * GWM);

    const size_t G4 = (size_t)G;
    const bool fc_ok  = (ws_size >= NEED_FC);
    const bool all_ok = (ws_size >= NEED_ALL);

    if (fc_ok)
        k_conv<<<4096, 256, 0, stream>>>(Wfc, Whr);

    if (all_ok) {
        k_conv_g2<<<4096, 256, 0, stream>>>(Wih, Whh, gw2[0][0], gw2[0][1]);
        k_conv_g2<<<4096, 256, 0, stream>>>(Wih + G4 * EMBD, Whh + G4 * HID,
                                            gw2[1][0], gw2[1][1]);
        k_init_m<<<B, 256, 0, stream>>>(x, emb, xcur, ws + o_st,
                                        xHi, xMid, h0Hi, h0Mid, h1Hi, h1Mid);
        for (int t = 0; t < TS; t++) {
            k_layer_f<<<256, 1024, 0, stream>>>(
                gw2[0][0], gw2[0][1], xHi, xMid, h0Hi, h0Mid,
                bih, bhh, c0, h0Hi, h0Mid, nullptr);
            k_layer_f<<<256, 1024, 0, stream>>>(
                gw2[1][0], gw2[1][1], h0Hi, h0Mid, h1Hi, h1Mid,
                bih + G, bhh + G, c1, h1Hi, h1Mid, h1);
            k_fc_mfma<<<NFM, 512, 0, stream>>>(Whr, h1Hi, bfc, x, t,
                                               psum, pm1, pm2, pi1, pi2, lt);
            k_fin2<<<B, 512, 0, stream>>>(psum, pm1, pm2, pi1, pi2, lt,
                                          h1, Wfc, bfc, emb, xcur,
                                          xHi, xMid, out, t);
        }
        return;
    }

    // ---- R14 tier: f32 gates + MFMA FC + separate fin ----
    k_init<<<B, 256, 0, stream>>>(x, emb, xcur, ws + o_st);
    for (int t = 0; t < TS; t++) {
        k_layer<<<dim3(32, KSL), 512, 0, stream>>>(xcur, h0, Wih, Whh, gpart);
        k_act<<<128, 256, 0, stream>>>(gpart, bih, bhh, c0, h0, hbr);
        k_layer<<<dim3(32, KSL), 512, 0, stream>>>(h0, h1, Wih + G4 * EMBD,
                                                   Whh + G4 * HID, gpart);
        k_act<<<128, 256, 0, stream>>>(gpart, bih + G, bhh + G, c1, h1, hbr);
        k_fc_mfma<<<NFM, 512, 0, stream>>>(Whr, hbr, bfc, x, t,
                                           psum, pm1, pm2, pi1, pi2, lt);
        k_fin2<<<B, 512, 0, stream>>>(psum, pm1, pm2, pi1, pi2, lt,
                                      h1, Wfc, bfc, emb, xcur,
                                      hbr, hbr, out, t);
    }
}